// Round 8
// baseline (261.786 us; speedup 1.0000x reference)
//
#include <hip/hip_runtime.h>
#include <math.h>

// FourierKNOConv2d: x[8,32,256,256] f32, kernel[2,1,32,32,32,2] f32, r scalar.
// out[8,32,256,256] f32.
//   kP:  Kp = (kr + i ki)^r                                 [2,32,32,32] c64
//   kA1: real FFT8 over x2 (x = x1+32*x2), streaming global->global:
//        F[rowblk][slot<8][rl<32][x1<32], slots [F0,F4,F1r,F1i,F2r,F2i,F3r,F3i]
//        F is 2048*8*32*32 floats = 64 MB (same count as X!)
//   kA2: Z1[row,w] = sum_{x1<32} F-combine(w&7) e^{-2pi i w x1/256}
//        (quad-phasor over x1, 8 iters, streaming L2-hot reads; math == R5 kA)
//   kB1: in-place radix-8 over y2:  S[y1,p] = sum_{y2<8} z1[y1+32y2] e^{-2pi i p y2/8}
//   kB2: Z2[bc,t,w] = sum_{y1<32} S[y1, t&7, w] e^{-2pi i h(t) y1/256},
//        h(t)=t<32?t:192+t
//   kC:  G = idft32_ch( dft32_ch(z2) * Kp ) / 8192   (8-mode blocks)
//   kD1: U[bc,y1,p,w] = sum_{t&7=p} G[bc,t,w] e^{+2pi i h(t) y1/256}
//   kDE: phase2: T[y,w] = sum_p U[y&31,p,w] e^{+2pi i p (y>>5)/8}  (8 iters)
//        phase3: out[row,x] = C(x)-S(x), out[row,256-x]=C(x)+S(x)  (x-symmetry)
// ws map, SPLIT path (needs >= 110 MB; harness fillBuffer shows 256 MiB ws):
//   F @0..64M, z1 @64..80M, z2 @80..88M, kp @88..88.5M, g @89..93M, U @93..109M
//   (fully disjoint — R7's bug was F sized 16M instead of 64M, aliasing all)
// ws map, FALLBACK path (ws < 110 MB; R5's proven 24.5 MB layout + LDS kA):
//   z1 @0..16M, z2 @16..24M, kp @24..24.5M, g @0..4M, U @4..21M

#define TWO_PI 6.28318530717958647692f

__global__ __launch_bounds__(256) void kP(const float* __restrict__ kin,
                                          const float* __restrict__ rp,
                                          float2* __restrict__ kp) {
  const int i = blockIdx.x * 256 + threadIdx.x;  // < 65536
  const float r = rp[0];
  const float kr = kin[2 * i], ki = kin[2 * i + 1];
  const float m2 = fmaf(kr, kr, ki * ki);
  float2 o = make_float2(0.f, 0.f);
  if (m2 > 0.f) {
    const float lm = 0.5f * logf(m2);
    const float ang = atan2f(ki, kr);
    const float mag = expf(r * lm);
    float s, c;
    sincosf(r * ang, &s, &c);
    o = make_float2(mag * c, mag * s);
  }
  kp[i] = o;
}

// kA1: 2048 blocks (rowblk of 32 rows); thread = (x1=tid&31, rr=tid>>5),
// 4 FFT8s (rows rr+8k). Reads coalesced (lane=x1, 4B stride); writes
// F[rb][s][rl][x1] coalesced (lane=x1). No LDS, no syncthreads -> full MLP.
__global__ __launch_bounds__(256) void kA1(const float* __restrict__ x,
                                           float* __restrict__ F) {
  const int tid = threadIdx.x;
  const int x1 = tid & 31, rr = tid >> 5;
  const long rb = blockIdx.x;
  const float* xb = x + rb * 32 * 256 + x1;
  float* Fb = F + rb * 8192 + x1;
  const float RT = 0.70710678118654752440f;
#pragma unroll
  for (int k = 0; k < 4; ++k) {
    const int rl = rr + 8 * k;
    const float* xr = xb + rl * 256;
    const float a0 = xr[0],   a1 = xr[32],  a2 = xr[64],  a3 = xr[96];
    const float a4 = xr[128], a5 = xr[160], a6 = xr[192], a7 = xr[224];
    const float t0 = a0 + a4, t1 = a0 - a4, t2 = a2 + a6, t3 = a2 - a6;
    const float u0 = a1 + a5, u1 = a1 - a5, u2 = a3 + a7, u3 = a3 - a7;
    const float E0 = t0 + t2, O0 = u0 + u2;
    const float d1 = RT * (u1 - u3), d2 = RT * (u1 + u3);
    float* Fo = Fb + rl * 32;
    Fo[0]        = E0 + O0;      // F0
    Fo[1024]     = E0 - O0;      // F4
    Fo[2 * 1024] = t1 + d1;      // F1r
    Fo[3 * 1024] = -(t3 + d2);   // F1i
    Fo[4 * 1024] = t0 - t2;      // F2r
    Fo[5 * 1024] = -(u0 - u2);   // F2i
    Fo[6 * 1024] = t1 - d1;      // F3r
    Fo[7 * 1024] = t3 - d2;      // F3i
  }
}

// kA2: 2048 blocks; thread = (w=tid&31, rq=tid>>5 -> rows 4rq..4rq+3).
// p=w&7 -> slots (pr,pi) + conj sign si (F_{8-p}=conj(F_p), X real).
// Quad phasor P[m]=e^{-2pi i w(4j+m)/256}, stepped by e^{-2pi i 4w/256};
// per j: 8 global b128 (L2-hot, reused in block) + 64 FMA. x1 ascending
// accumulation order == R5 kA pass3 (same rounding class).
__global__ __launch_bounds__(256) void kA2(const float* __restrict__ F,
                                           float2* __restrict__ z1) {
  const int tid = threadIdx.x;
  const int w = tid & 31, rq = tid >> 5;
  const long rb = blockIdx.x;
  const int p = w & 7;
  int pr, pi;
  float si;
  if (p == 0)      { pr = 0;           pi = 0;      si = 0.f; }
  else if (p == 4) { pr = 1;           pi = 1;      si = 0.f; }
  else if (p < 4)  { pr = 2 * p;       pi = pr + 1; si = 1.f; }
  else             { pr = 2 * (8 - p); pi = pr + 1; si = -1.f; }
  const float* Fr_ = F + rb * 8192 + pr * 1024 + rq * 128;
  const float* Fi_ = F + rb * 8192 + pi * 1024 + rq * 128;
  float s1, c1;
  sincosf(-TWO_PI * (float)w / 256.0f, &s1, &c1);
  float Pc[4], Ps[4];
  Pc[0] = 1.f; Ps[0] = 0.f;
  Pc[1] = c1;  Ps[1] = s1;
  Pc[2] = fmaf(c1, c1, -s1 * s1);
  Ps[2] = 2.f * c1 * s1;
  Pc[3] = fmaf(Pc[2], c1, -Ps[2] * s1);
  Ps[3] = fmaf(Pc[2], s1, Ps[2] * c1);
  const float c4 = fmaf(Pc[3], c1, -Ps[3] * s1);
  const float s4 = fmaf(Pc[3], s1, Ps[3] * c1);
  float Cr[4] = {0.f, 0.f, 0.f, 0.f}, Ci[4] = {0.f, 0.f, 0.f, 0.f};
#pragma unroll
  for (int j = 0; j < 8; ++j) {
    float4 fr[4], fi[4];
#pragma unroll
    for (int r = 0; r < 4; ++r) {
      fr[r] = *(const float4*)(Fr_ + r * 32 + 4 * j);
      fi[r] = *(const float4*)(Fi_ + r * 32 + 4 * j);
    }
    const float qs0 = si * Ps[0], qc0 = si * Pc[0];
    const float qs1 = si * Ps[1], qc1 = si * Pc[1];
    const float qs2 = si * Ps[2], qc2 = si * Pc[2];
    const float qs3 = si * Ps[3], qc3 = si * Pc[3];
#pragma unroll
    for (int r = 0; r < 4; ++r) {
      float cr = Cr[r], ci = Ci[r];
      cr = fmaf(fr[r].x, Pc[0], fmaf(-fi[r].x, qs0, cr));
      ci = fmaf(fr[r].x, Ps[0], fmaf( fi[r].x, qc0, ci));
      cr = fmaf(fr[r].y, Pc[1], fmaf(-fi[r].y, qs1, cr));
      ci = fmaf(fr[r].y, Ps[1], fmaf( fi[r].y, qc1, ci));
      cr = fmaf(fr[r].z, Pc[2], fmaf(-fi[r].z, qs2, cr));
      ci = fmaf(fr[r].z, Ps[2], fmaf( fi[r].z, qc2, ci));
      cr = fmaf(fr[r].w, Pc[3], fmaf(-fi[r].w, qs3, cr));
      ci = fmaf(fr[r].w, Ps[3], fmaf( fi[r].w, qc3, ci));
      Cr[r] = cr; Ci[r] = ci;
    }
#pragma unroll
    for (int m = 0; m < 4; ++m) {
      const float tn = fmaf(Pc[m], c4, -Ps[m] * s4);
      Ps[m] = fmaf(Pc[m], s4, Ps[m] * c4);
      Pc[m] = tn;
    }
  }
  float2* o = z1 + (rb * 32 + 4 * rq) * 32 + w;
  o[0]  = make_float2(Cr[0], Ci[0]);
  o[32] = make_float2(Cr[1], Ci[1]);
  o[64] = make_float2(Cr[2], Ci[2]);
  o[96] = make_float2(Cr[3], Ci[3]);
}

// kA (fallback, R5's proven LDS version): 2048 blocks; block = 32 rows.
// LDS 32 KB, rotate-swizzle idx(x,r) = x*32 + ((r + 4x) & 31).
__global__ __launch_bounds__(256) void kA(const float* __restrict__ x,
                                          float2* __restrict__ z1) {
  __shared__ float xs[8192];  // 32 KB
  const int tid = threadIdx.x;
  const long row0 = (long)blockIdx.x * 32;
  const float* xg = x + row0 * 256;
  {
    const int xl = tid & 31, rq = tid >> 5;
    const float* xgr = xg + rq * 4 * 256 + xl;
#pragma unroll
    for (int cb = 0; cb < 8; ++cb) {
      const int xc = xl + 32 * cb;
      const float4 v = make_float4(xgr[32 * cb], xgr[32 * cb + 256],
                                   xgr[32 * cb + 512], xgr[32 * cb + 768]);
      *(float4*)(xs + xc * 32 + 4 * ((rq + xc) & 7)) = v;
    }
  }
  __syncthreads();
  const float RT = 0.70710678118654752440f;
#pragma unroll
  for (int k = 0; k < 4; ++k) {
    const int i = tid + (k << 8);
    const int x1 = i >> 5, r = i & 31;
    float* base = xs + x1 * 32 + ((r + 4 * x1) & 31);
    const float a0 = base[0],        a1 = base[1024],     a2 = base[2048];
    const float a3 = base[3 * 1024], a4 = base[4 * 1024], a5 = base[5 * 1024];
    const float a6 = base[6 * 1024], a7 = base[7 * 1024];
    const float t0 = a0 + a4, t1 = a0 - a4, t2 = a2 + a6, t3 = a2 - a6;
    const float u0 = a1 + a5, u1 = a1 - a5, u2 = a3 + a7, u3 = a3 - a7;
    const float E0 = t0 + t2, O0 = u0 + u2;
    const float d1 = RT * (u1 - u3), d2 = RT * (u1 + u3);
    base[0]        = E0 + O0;
    base[1024]     = E0 - O0;
    base[2 * 1024] = t1 + d1;
    base[3 * 1024] = -(t3 + d2);
    base[4 * 1024] = t0 - t2;
    base[5 * 1024] = -(u0 - u2);
    base[6 * 1024] = t1 - d1;
    base[7 * 1024] = t3 - d2;
  }
  __syncthreads();
  const int w = tid & 31;
  const int r0 = (tid >> 5) << 2;
  const int p = w & 7;
  int pr, pi;
  float si;
  if (p == 0)      { pr = 0;           pi = 0;      si = 0.f; }
  else if (p == 4) { pr = 1;           pi = 1;      si = 0.f; }
  else if (p < 4)  { pr = 2 * p;       pi = pr + 1; si = 1.f; }
  else             { pr = 2 * (8 - p); pi = pr + 1; si = -1.f; }
  const char* ur = (const char*)xs + pr * 4096;
  const char* ui = (const char*)xs + pi * 4096;
  const char* urp[8];
  const char* uip[8];
#pragma unroll
  for (int j = 0; j < 8; ++j) {
    const int off = 4 * ((r0 + 4 * j) & 31) + 128 * j;
    urp[j] = ur + off;
    uip[j] = ui + off;
  }
  float s1, c1;
  sincosf(-TWO_PI * (float)w / 256.0f, &s1, &c1);
  float pc = 1.f, ps = 0.f;
  float Cr0 = 0, Cr1 = 0, Cr2 = 0, Cr3 = 0;
  float Ci0 = 0, Ci1 = 0, Ci2 = 0, Ci3 = 0;
#pragma unroll
  for (int bq = 0; bq < 4; ++bq) {
#pragma unroll
    for (int j = 0; j < 8; ++j) {
      const float4 Fr = *(const float4*)(urp[j] + bq * 1024);
      const float4 Fi = *(const float4*)(uip[j] + bq * 1024);
      const float qs = si * ps, qc = si * pc;
      Cr0 = fmaf(Fr.x, pc, fmaf(-Fi.x, qs, Cr0));
      Ci0 = fmaf(Fr.x, ps, fmaf( Fi.x, qc, Ci0));
      Cr1 = fmaf(Fr.y, pc, fmaf(-Fi.y, qs, Cr1));
      Ci1 = fmaf(Fr.y, ps, fmaf( Fi.y, qc, Ci1));
      Cr2 = fmaf(Fr.z, pc, fmaf(-Fi.z, qs, Cr2));
      Ci2 = fmaf(Fr.z, ps, fmaf( Fi.z, qc, Ci2));
      Cr3 = fmaf(Fr.w, pc, fmaf(-Fi.w, qs, Cr3));
      Ci3 = fmaf(Fr.w, ps, fmaf( Fi.w, qc, Ci3));
      const float tn = fmaf(pc, c1, -ps * s1);
      ps = fmaf(pc, s1, ps * c1);
      pc = tn;
    }
  }
  float2* o = z1 + (row0 + r0) * 32 + w;
  o[0]  = make_float2(Cr0, Ci0);
  o[32] = make_float2(Cr1, Ci1);
  o[64] = make_float2(Cr2, Ci2);
  o[96] = make_float2(Cr3, Ci3);
}

// kB1: in-place FFT-8 over y2. 1024 blocks x 256 thr = 1 thread per (bc,y1,w).
__global__ __launch_bounds__(256) void kB1(float2* __restrict__ z1) {
  const int gt = blockIdx.x * 256 + threadIdx.x;  // < 262144
  const int w = gt & 31, y1 = (gt >> 5) & 31, bc = gt >> 10;
  float2* base = z1 + (long)bc * 8192 + y1 * 32 + w;  // +j*1024 per y2-step
  float2 a[8];
#pragma unroll
  for (int j = 0; j < 8; ++j) a[j] = base[j * 1024];
  float2 t0 = make_float2(a[0].x + a[4].x, a[0].y + a[4].y);
  float2 t1 = make_float2(a[0].x - a[4].x, a[0].y - a[4].y);
  float2 t2 = make_float2(a[2].x + a[6].x, a[2].y + a[6].y);
  float2 t3 = make_float2(a[2].x - a[6].x, a[2].y - a[6].y);
  const float2 E0 = make_float2(t0.x + t2.x, t0.y + t2.y);
  const float2 E2 = make_float2(t0.x - t2.x, t0.y - t2.y);
  const float2 E1 = make_float2(t1.x + t3.y, t1.y - t3.x);  // t1 - i*t3
  const float2 E3 = make_float2(t1.x - t3.y, t1.y + t3.x);  // t1 + i*t3
  t0 = make_float2(a[1].x + a[5].x, a[1].y + a[5].y);
  t1 = make_float2(a[1].x - a[5].x, a[1].y - a[5].y);
  t2 = make_float2(a[3].x + a[7].x, a[3].y + a[7].y);
  t3 = make_float2(a[3].x - a[7].x, a[3].y - a[7].y);
  const float2 O0 = make_float2(t0.x + t2.x, t0.y + t2.y);
  const float2 O2 = make_float2(t0.x - t2.x, t0.y - t2.y);
  const float2 O1 = make_float2(t1.x + t3.y, t1.y - t3.x);
  const float2 O3 = make_float2(t1.x - t3.y, t1.y + t3.x);
  const float RT = 0.70710678118654752440f;
  const float2 B0 = O0;
  const float2 B1 = make_float2(RT * (O1.x + O1.y), RT * (O1.y - O1.x));
  const float2 B2 = make_float2(O2.y, -O2.x);  // -i*O2
  const float2 B3 = make_float2(RT * (O3.y - O3.x), -RT * (O3.x + O3.y));
  base[0]        = make_float2(E0.x + B0.x, E0.y + B0.y);
  base[1 * 1024] = make_float2(E1.x + B1.x, E1.y + B1.y);
  base[2 * 1024] = make_float2(E2.x + B2.x, E2.y + B2.y);
  base[3 * 1024] = make_float2(E3.x + B3.x, E3.y + B3.y);
  base[4 * 1024] = make_float2(E0.x - B0.x, E0.y - B0.y);
  base[5 * 1024] = make_float2(E1.x - B1.x, E1.y - B1.y);
  base[6 * 1024] = make_float2(E2.x - B2.x, E2.y - B2.y);
  base[7 * 1024] = make_float2(E3.x - B3.x, E3.y - B3.y);
}

// kB2: 2048 blocks = (bc, tq). Thread = (k=tid>>5 -> t=tq*8+k, w=tid&31).
__global__ __launch_bounds__(256) void kB2(const float2* __restrict__ s,
                                           float2* __restrict__ z2) {
  const int bc = blockIdx.x >> 3, tq = blockIdx.x & 7;
  const int k = threadIdx.x >> 5, w = threadIdx.x & 31;
  const int t = tq * 8 + k;
  const int h = (t < 32) ? t : (192 + t);
  float sr, cr;
  sincosf(-TWO_PI * (float)h / 256.0f, &sr, &cr);
  const float2* src = s + (long)bc * 8192 + k * 1024 + w;  // row y1+32k
  float ar = 0.f, ai = 0.f;
  float pc = 1.f, ps = 0.f;
  for (int y1 = 0; y1 < 32; ++y1) {
    const float2 v = src[y1 * 32];
    ar = fmaf(v.x, pc, fmaf(-v.y, ps, ar));
    ai = fmaf(v.x, ps, fmaf( v.y, pc, ai));
    const float tn = fmaf(pc, cr, -ps * sr);
    ps = fmaf(pc, sr, ps * cr);
    pc = tn;
  }
  z2[(long)bc * 2048 + t * 32 + w] = make_float2(ar, ai);
}

// kC: 2048 blocks; block = 8 modes (same b,t; 8 w). 1 output/thread/pass.
__global__ __launch_bounds__(256) void kC(const float2* __restrict__ z2,
                                          const float2* __restrict__ kp,
                                          float2* __restrict__ g) {
  __shared__ float2 z2s[8 * 33];
  __shared__ float2 fk[8 * 33];
  __shared__ float2 tw[32];
  const int tid = threadIdx.x;
  if (tid < 32) {
    float s, c;
    sincosf(-TWO_PI * (float)tid / 32.0f, &s, &c);
    tw[tid] = make_float2(c, s);
  }
  const int m0 = blockIdx.x * 8;
  const int b = m0 >> 11;
  const int twi = m0 & 2047;
  const int t = twi >> 5;
  const int w0 = twi & 31;
  const int s_ = t >> 5, tm = t & 31;
  {
    const int ci = tid >> 3, wj = tid & 7;
    z2s[wj * 33 + ci] = z2[((long)(b * 32 + ci)) * 2048 + t * 32 + w0 + wj];
  }
  __syncthreads();
  const int m = tid & 7;
  {
    const int cf = tid >> 3;
    float fr = 0, fi = 0;
    int i0 = 0;
#pragma unroll 8
    for (int ci = 0; ci < 32; ++ci) {
      const float2 z = z2s[m * 33 + ci];
      const float2 t0 = tw[i0]; i0 = (i0 + cf) & 31;
      fr = fmaf(z.x, t0.x, fmaf(-z.y, t0.y, fr));
      fi = fmaf(z.x, t0.y, fmaf( z.y, t0.x, fi));
    }
    const float2 k0 = kp[((s_ * 32 + cf) * 32 + tm) * 32 + w0 + m];
    fk[m * 33 + cf] = make_float2(fr * k0.x - fi * k0.y, fr * k0.y + fi * k0.x);
  }
  __syncthreads();
  {
    const int co = tid >> 3;
    float gr = 0, gi = 0;
    int i0 = 0;
#pragma unroll 8
    for (int cf = 0; cf < 32; ++cf) {
      const float2 f = fk[m * 33 + cf];
      const float2 t0 = tw[i0]; i0 = (i0 + co) & 31;
      gr = fmaf(f.x, t0.x, fmaf( f.y, t0.y, gr));
      gi = fmaf(f.y, t0.x, fmaf(-f.x, t0.y, gi));
    }
    const float SC = 1.0f / 8192.0f;
    g[((long)(b * 32 + co)) * 2048 + t * 32 + w0 + m] = make_float2(gr * SC, gi * SC);
  }
}

// kD1: U[bc,y1,p,w] = sum_{t&7=p} G[bc,t,w] e^{+2pi i h(t) y1/256}.
__global__ __launch_bounds__(256) void kD1(const float2* __restrict__ g,
                                           float2* __restrict__ U) {
  const int bc = blockIdx.x >> 3, y1q = blockIdx.x & 7;
  const int p = threadIdx.x >> 5, w = threadIdx.x & 31;
  const float2* gb = g + (long)bc * 2048 + w;         // + t*32
  float2* ub = U + (long)bc * 8192 + p * 32 + w;      // + y1*256
#pragma unroll
  for (int y1l = 0; y1l < 4; ++y1l) {
    const int y1 = y1q * 4 + y1l;
    float st, ct;   // step e^{+2pi i y1/32}
    sincosf(TWO_PI * (float)y1 / 32.0f, &st, &ct);
    float s1, c1;   // start group1: e^{+2pi i p y1/256}
    sincosf(TWO_PI * (float)((p * y1) & 255) / 256.0f, &s1, &c1);
    float s2, c2;   // start group2: e^{+2pi i (224+p) y1/256}
    sincosf(TWO_PI * (float)(((224 + p) * y1) & 255) / 256.0f, &s2, &c2);
    float ar = 0.f, ai = 0.f;
    float pc = c1, ps = s1, qc = c2, qs = s2;
#pragma unroll
    for (int j = 0; j < 4; ++j) {
      const float2 va = gb[(p + 8 * j) * 32];
      const float2 vb = gb[(32 + p + 8 * j) * 32];
      ar = fmaf(va.x, pc, fmaf(-va.y, ps, ar));
      ai = fmaf(va.x, ps, fmaf( va.y, pc, ai));
      ar = fmaf(vb.x, qc, fmaf(-vb.y, qs, ar));
      ai = fmaf(vb.x, qs, fmaf( vb.y, qc, ai));
      const float tn = fmaf(pc, ct, -ps * st);
      ps = fmaf(pc, st, ps * ct);
      pc = tn;
      const float tm2 = fmaf(qc, ct, -qs * st);
      qs = fmaf(qc, st, qs * ct);
      qc = tm2;
    }
    ub[y1 * 256] = make_float2(ar, ai);
  }
}

// kDE: 2048 blocks = (bc, yq); 32 rows/block.
__global__ __launch_bounds__(256) void kDE(const float2* __restrict__ U,
                                           float* __restrict__ out) {
  __shared__ float2 tst[32 * 34]; // 8.5 KB
  const int tid = threadIdx.x;
  const int bc = blockIdx.x >> 3, yq = blockIdx.x & 7;
  {  // phase 2
    const int y5 = tid >> 3, wq = tid & 7;  // w = wq*4 + kk
    const float* ub = (const float*)(U + (long)bc * 8192 + (long)y5 * 256 + wq * 4);
    float Tr[4] = {0.f, 0.f, 0.f, 0.f}, Ti[4] = {0.f, 0.f, 0.f, 0.f};
#pragma unroll
    for (int p = 0; p < 8; ++p) {
      float sp, cp;
      sincosf(TWO_PI * (float)((p * yq) & 7) / 8.0f, &sp, &cp);
      const float4 qa = *(const float4*)(ub + p * 64);
      const float4 qb = *(const float4*)(ub + p * 64 + 4);
      Tr[0] = fmaf(qa.x, cp, fmaf(-qa.y, sp, Tr[0]));
      Ti[0] = fmaf(qa.x, sp, fmaf( qa.y, cp, Ti[0]));
      Tr[1] = fmaf(qa.z, cp, fmaf(-qa.w, sp, Tr[1]));
      Ti[1] = fmaf(qa.z, sp, fmaf( qa.w, cp, Ti[1]));
      Tr[2] = fmaf(qb.x, cp, fmaf(-qb.y, sp, Tr[2]));
      Ti[2] = fmaf(qb.x, sp, fmaf( qb.y, cp, Ti[2]));
      Tr[3] = fmaf(qb.z, cp, fmaf(-qb.w, sp, Tr[3]));
      Ti[3] = fmaf(qb.z, sp, fmaf( qb.w, cp, Ti[3]));
    }
#pragma unroll
    for (int kk = 0; kk < 4; ++kk) {
      const int w = wq * 4 + kk;
      const float sc = w ? (2.0f / 256.0f) : (1.0f / 256.0f);
      tst[w * 34 + y5] = make_float2(Tr[kk] * sc, Ti[kk] * sc);
    }
  }
  __syncthreads();
  {  // phase 3
    const int xq = tid & 31;  // x = xq + 32*m
    const int rh = tid >> 5;  // rows rh*4 .. rh*4+3
    float sb, cb;
    sincosf(TWO_PI * (float)xq / 256.0f, &sb, &cb);
    const float RT = 0.70710678118654752440f;
    const float stc1 = RT * (cb - sb), sts1 = RT * (cb + sb);
    const float stc[4] = {cb, stc1, -sb, -sts1};
    const float sts[4] = {sb, sts1, cb, stc1};
    float C[4][4], S[4][4];
#pragma unroll
    for (int m = 0; m < 4; ++m)
#pragma unroll
      for (int j = 0; j < 4; ++j) { C[m][j] = 0.f; S[m][j] = 0.f; }
    float pc[4] = {1.f, 1.f, 1.f, 1.f}, ps[4] = {0.f, 0.f, 0.f, 0.f};
    const float* tbse = (const float*)tst + rh * 8;
#pragma unroll 2
    for (int w = 0; w < 32; ++w) {
      const float4 q0 = *(const float4*)(tbse + w * 68);      // rows 4rh, 4rh+1
      const float4 q1 = *(const float4*)(tbse + w * 68 + 4);  // rows 4rh+2, 4rh+3
#pragma unroll
      for (int m = 0; m < 4; ++m) {
        C[m][0] = fmaf(q0.x, pc[m], C[m][0]);
        S[m][0] = fmaf(q0.y, ps[m], S[m][0]);
        C[m][1] = fmaf(q0.z, pc[m], C[m][1]);
        S[m][1] = fmaf(q0.w, ps[m], S[m][1]);
        C[m][2] = fmaf(q1.x, pc[m], C[m][2]);
        S[m][2] = fmaf(q1.y, ps[m], S[m][2]);
        C[m][3] = fmaf(q1.z, pc[m], C[m][3]);
        S[m][3] = fmaf(q1.w, ps[m], S[m][3]);
        const float tn = fmaf(pc[m], stc[m], -ps[m] * sts[m]);
        ps[m] = fmaf(pc[m], sts[m], ps[m] * stc[m]);
        pc[m] = tn;
      }
    }
    const long rbase = (long)bc * 256 + yq * 32;
#pragma unroll
    for (int m = 0; m < 4; ++m) {
      const int xx = xq + 32 * m;
#pragma unroll
      for (int j = 0; j < 4; ++j) {
        const long row = rbase + rh * 4 + j;
        out[row * 256 + xx] = C[m][j] - S[m][j];
        out[row * 256 + ((256 - xx) & 255)] = C[m][j] + S[m][j];
      }
    }
    if (tid < 32) {  // column x=128: sum (-1)^w a_w
      float ae = 0.f, ao = 0.f;
#pragma unroll
      for (int k = 0; k < 16; ++k) {
        ae += tst[(2 * k) * 34 + tid].x;
        ao += tst[(2 * k + 1) * 34 + tid].x;
      }
      out[(rbase + tid) * 256 + 128] = ae - ao;
    }
  }
}

extern "C" void kernel_launch(void* const* d_in, const int* in_sizes, int n_in,
                              void* d_out, int out_size, void* d_ws, size_t ws_size,
                              hipStream_t stream) {
  const float* x = (const float*)d_in[0];
  const float* kin = (const float*)d_in[1];
  const float* rp = (const float*)d_in[2];
  float* out = (float*)d_out;
  char* ws = (char*)d_ws;

  if (ws_size >= (110ull << 20)) {
    // SPLIT path: fully disjoint, 109 MB.
    float*  F  = (float*)(ws);                    // 0..64M  (kA1 w, kA2 r)
    float2* z1 = (float2*)(ws + (64ull << 20));   // 64..80M (kA2 w, kB1 rw, kB2 r)
    float2* z2 = (float2*)(ws + (80ull << 20));   // 80..88M (kB2 w, kC r)
    float2* kp = (float2*)(ws + (88ull << 20));   // 88..88.5M (kP w, kC r)
    float2* g  = (float2*)(ws + (89ull << 20));   // 89..93M (kC w, kD1 r)
    float2* U  = (float2*)(ws + (93ull << 20));   // 93..109M (kD1 w, kDE r)
    kP<<<256, 256, 0, stream>>>(kin, rp, kp);
    kA1<<<2048, 256, 0, stream>>>(x, F);
    kA2<<<2048, 256, 0, stream>>>(F, z1);
    kB1<<<1024, 256, 0, stream>>>(z1);
    kB2<<<2048, 256, 0, stream>>>(z1, z2);
    kC<<<2048, 256, 0, stream>>>(z2, kp, g);
    kD1<<<2048, 256, 0, stream>>>(g, U);
    kDE<<<2048, 256, 0, stream>>>(U, out);
  } else {
    // FALLBACK: R5's proven 24.5 MB layout + LDS kA.
    float2* z1 = (float2*)(ws);                   // 0..16M
    float2* z2 = (float2*)(ws + (16ull << 20));   // 16..24M
    float2* kp = (float2*)(ws + (24ull << 20));   // 24..24.5M
    float2* g  = (float2*)(ws);                   // 0..4M (over dead z1)
    float2* U  = (float2*)(ws + (4ull << 20));    // 4..21M (over dead z1)
    kP<<<256, 256, 0, stream>>>(kin, rp, kp);
    kA<<<2048, 256, 0, stream>>>(x, z1);
    kB1<<<1024, 256, 0, stream>>>(z1);
    kB2<<<2048, 256, 0, stream>>>(z1, z2);
    kC<<<2048, 256, 0, stream>>>(z2, kp, g);
    kD1<<<2048, 256, 0, stream>>>(g, U);
    kDE<<<2048, 256, 0, stream>>>(U, out);
  }
}

// Round 9
// 197.760 us; speedup vs baseline: 1.3238x; 1.3238x over previous
//
#include <hip/hip_runtime.h>
#include <math.h>

// FourierKNOConv2d: x[8,32,256,256] f32, kernel[2,1,32,32,32,2] f32, r scalar.
// out[8,32,256,256] f32.
//   kP:   Kp = (kr + i ki)^r                                [2,32,32,32] c64
//   kA:   Z1[row,w] = sum_x X[row,x] e^{-2pi i w x/256}, w<32
//         via x = x1+32*x2: in-LDS real FFT8 over x2, then 32-term phasor sum.
//   kB:   fused per-bc: stage z1[bc] (64KB) -> LDS, FFT8 over y2 in LDS
//         (S[y1,p] at LDS row y1+32p), then
//         Z2[bc,t,w] = sum_{y1<32} S[y1,t&7,w] e^{-2pi i h(t) y1/256},
//         h(t)=t<32?t:192+t. Grid 512=(bc,th half of t). z1 global read-only.
//   kC:   G = idft32_ch( dft32_ch(z2) * Kp ) / 8192   (8-mode blocks)
//   kDE2: fused per-bc: stage g[bc] (16KB) -> LDS;
//         phase a: thread (y1,w) holds U[p<8] in regs:
//                  U[p] = sum_{t&7=p} G[t,w] e^{+2pi i h(t) y1/256} (64-t loop)
//         per yq: phase b: T[y1+32yq,w] = sum_p U[p] e^{+2pi i p yq/8} -> tst
//                 phase c (kE): out[row,x]=C-S, out[row,256-x]=C+S (x-symmetry)
//         Grid 512=(bc,yh half of yq), 512 thr. No U/tb global buffers.
// ws map (24.5 MB, stream-ordered reuse):
//   z1 @0..16M (kA w, kB r), z2 @16..24M (kB w, kC r), kp @24..24.5M,
//   g @0..4M (kC w, kDE2 r; over dead z1)

#define TWO_PI 6.28318530717958647692f

__global__ __launch_bounds__(256) void kP(const float* __restrict__ kin,
                                          const float* __restrict__ rp,
                                          float2* __restrict__ kp) {
  const int i = blockIdx.x * 256 + threadIdx.x;  // < 65536
  const float r = rp[0];
  const float kr = kin[2 * i], ki = kin[2 * i + 1];
  const float m2 = fmaf(kr, kr, ki * ki);
  float2 o = make_float2(0.f, 0.f);
  if (m2 > 0.f) {
    const float lm = 0.5f * logf(m2);
    const float ang = atan2f(ki, kr);
    const float mag = expf(r * lm);
    float s, c;
    sincosf(r * ang, &s, &c);
    o = make_float2(mag * c, mag * s);
  }
  kp[i] = o;
}

// kA (R5 proven): 2048 blocks; block = 32 rows. LDS 32 KB, rotate-swizzle
// idx(x,r) = x*32 + ((r + 4x) & 31). Pass2: in-LDS real FFT8 over x2.
// Pass3: 32-term phasor sum with precomputed swizzled pointers.
__global__ __launch_bounds__(256) void kA(const float* __restrict__ x,
                                          float2* __restrict__ z1) {
  __shared__ float xs[8192];  // 32 KB
  const int tid = threadIdx.x;
  const long row0 = (long)blockIdx.x * 32;
  const float* xg = x + row0 * 256;
  {
    const int xl = tid & 31, rq = tid >> 5;
    const float* xgr = xg + rq * 4 * 256 + xl;
#pragma unroll
    for (int cb = 0; cb < 8; ++cb) {
      const int xc = xl + 32 * cb;
      const float4 v = make_float4(xgr[32 * cb], xgr[32 * cb + 256],
                                   xgr[32 * cb + 512], xgr[32 * cb + 768]);
      *(float4*)(xs + xc * 32 + 4 * ((rq + xc) & 7)) = v;
    }
  }
  __syncthreads();
  const float RT = 0.70710678118654752440f;
#pragma unroll
  for (int k = 0; k < 4; ++k) {
    const int i = tid + (k << 8);
    const int x1 = i >> 5, r = i & 31;
    float* base = xs + x1 * 32 + ((r + 4 * x1) & 31);
    const float a0 = base[0],        a1 = base[1024],     a2 = base[2048];
    const float a3 = base[3 * 1024], a4 = base[4 * 1024], a5 = base[5 * 1024];
    const float a6 = base[6 * 1024], a7 = base[7 * 1024];
    const float t0 = a0 + a4, t1 = a0 - a4, t2 = a2 + a6, t3 = a2 - a6;
    const float u0 = a1 + a5, u1 = a1 - a5, u2 = a3 + a7, u3 = a3 - a7;
    const float E0 = t0 + t2, O0 = u0 + u2;
    const float d1 = RT * (u1 - u3), d2 = RT * (u1 + u3);
    base[0]        = E0 + O0;
    base[1024]     = E0 - O0;
    base[2 * 1024] = t1 + d1;
    base[3 * 1024] = -(t3 + d2);
    base[4 * 1024] = t0 - t2;
    base[5 * 1024] = -(u0 - u2);
    base[6 * 1024] = t1 - d1;
    base[7 * 1024] = t3 - d2;
  }
  __syncthreads();
  const int w = tid & 31;
  const int r0 = (tid >> 5) << 2;
  const int p = w & 7;
  int pr, pi;
  float si;
  if (p == 0)      { pr = 0;           pi = 0;      si = 0.f; }
  else if (p == 4) { pr = 1;           pi = 1;      si = 0.f; }
  else if (p < 4)  { pr = 2 * p;       pi = pr + 1; si = 1.f; }
  else             { pr = 2 * (8 - p); pi = pr + 1; si = -1.f; }
  const char* ur = (const char*)xs + pr * 4096;
  const char* ui = (const char*)xs + pi * 4096;
  const char* urp[8];
  const char* uip[8];
#pragma unroll
  for (int j = 0; j < 8; ++j) {
    const int off = 4 * ((r0 + 4 * j) & 31) + 128 * j;
    urp[j] = ur + off;
    uip[j] = ui + off;
  }
  float s1, c1;
  sincosf(-TWO_PI * (float)w / 256.0f, &s1, &c1);
  float pc = 1.f, ps = 0.f;
  float Cr0 = 0, Cr1 = 0, Cr2 = 0, Cr3 = 0;
  float Ci0 = 0, Ci1 = 0, Ci2 = 0, Ci3 = 0;
#pragma unroll
  for (int bq = 0; bq < 4; ++bq) {
#pragma unroll
    for (int j = 0; j < 8; ++j) {
      const float4 Fr = *(const float4*)(urp[j] + bq * 1024);
      const float4 Fi = *(const float4*)(uip[j] + bq * 1024);
      const float qs = si * ps, qc = si * pc;
      Cr0 = fmaf(Fr.x, pc, fmaf(-Fi.x, qs, Cr0));
      Ci0 = fmaf(Fr.x, ps, fmaf( Fi.x, qc, Ci0));
      Cr1 = fmaf(Fr.y, pc, fmaf(-Fi.y, qs, Cr1));
      Ci1 = fmaf(Fr.y, ps, fmaf( Fi.y, qc, Ci1));
      Cr2 = fmaf(Fr.z, pc, fmaf(-Fi.z, qs, Cr2));
      Ci2 = fmaf(Fr.z, ps, fmaf( Fi.z, qc, Ci2));
      Cr3 = fmaf(Fr.w, pc, fmaf(-Fi.w, qs, Cr3));
      Ci3 = fmaf(Fr.w, ps, fmaf( Fi.w, qc, Ci3));
      const float tn = fmaf(pc, c1, -ps * s1);
      ps = fmaf(pc, s1, ps * c1);
      pc = tn;
    }
  }
  float2* o = z1 + (row0 + r0) * 32 + w;
  o[0]  = make_float2(Cr0, Ci0);
  o[32] = make_float2(Cr1, Ci1);
  o[64] = make_float2(Cr2, Ci2);
  o[96] = make_float2(Cr3, Ci3);
}

// kB: fused kB1+kB2 per bc. 512 blocks = (bc, th); 256 thr; 64 KB LDS.
// Stage z1[bc] -> zs[256][32]; FFT8 over y2 in LDS (pair (y1,w), cell stride
// 1024 float2, in-place, exclusive ownership); then thread = (lt=tid>>5 -> p,
// w=tid&31) computes 4 t-outputs t = th*32+lt+8q sharing one LDS read per y1.
__global__ __launch_bounds__(256) void kB(const float2* __restrict__ z1,
                                          float2* __restrict__ z2) {
  __shared__ float2 zs[8192];  // 64 KB
  const int tid = threadIdx.x;
  const int bc = blockIdx.x >> 1, th = blockIdx.x & 1;
  {
    const float4* s4 = (const float4*)(z1 + (long)bc * 8192);
    float4* d4 = (float4*)zs;
    for (int i = tid; i < 4096; i += 256) d4[i] = s4[i];
  }
  __syncthreads();
  const float RT = 0.70710678118654752440f;
#pragma unroll
  for (int e = 0; e < 4; ++e) {
    float2* base = zs + tid + (e << 8);  // cell (y1,w), + j*1024 per y2
    float2 a[8];
#pragma unroll
    for (int j = 0; j < 8; ++j) a[j] = base[j * 1024];
    float2 t0 = make_float2(a[0].x + a[4].x, a[0].y + a[4].y);
    float2 t1 = make_float2(a[0].x - a[4].x, a[0].y - a[4].y);
    float2 t2 = make_float2(a[2].x + a[6].x, a[2].y + a[6].y);
    float2 t3 = make_float2(a[2].x - a[6].x, a[2].y - a[6].y);
    const float2 E0 = make_float2(t0.x + t2.x, t0.y + t2.y);
    const float2 E2 = make_float2(t0.x - t2.x, t0.y - t2.y);
    const float2 E1 = make_float2(t1.x + t3.y, t1.y - t3.x);  // t1 - i*t3
    const float2 E3 = make_float2(t1.x - t3.y, t1.y + t3.x);  // t1 + i*t3
    t0 = make_float2(a[1].x + a[5].x, a[1].y + a[5].y);
    t1 = make_float2(a[1].x - a[5].x, a[1].y - a[5].y);
    t2 = make_float2(a[3].x + a[7].x, a[3].y + a[7].y);
    t3 = make_float2(a[3].x - a[7].x, a[3].y - a[7].y);
    const float2 O0 = make_float2(t0.x + t2.x, t0.y + t2.y);
    const float2 O2 = make_float2(t0.x - t2.x, t0.y - t2.y);
    const float2 O1 = make_float2(t1.x + t3.y, t1.y - t3.x);
    const float2 O3 = make_float2(t1.x - t3.y, t1.y + t3.x);
    const float2 B0 = O0;
    const float2 B1 = make_float2(RT * (O1.x + O1.y), RT * (O1.y - O1.x));
    const float2 B2 = make_float2(O2.y, -O2.x);  // -i*O2
    const float2 B3 = make_float2(RT * (O3.y - O3.x), -RT * (O3.x + O3.y));
    base[0]        = make_float2(E0.x + B0.x, E0.y + B0.y);
    base[1 * 1024] = make_float2(E1.x + B1.x, E1.y + B1.y);
    base[2 * 1024] = make_float2(E2.x + B2.x, E2.y + B2.y);
    base[3 * 1024] = make_float2(E3.x + B3.x, E3.y + B3.y);
    base[4 * 1024] = make_float2(E0.x - B0.x, E0.y - B0.y);
    base[5 * 1024] = make_float2(E1.x - B1.x, E1.y - B1.y);
    base[6 * 1024] = make_float2(E2.x - B2.x, E2.y - B2.y);
    base[7 * 1024] = make_float2(E3.x - B3.x, E3.y - B3.y);
  }
  __syncthreads();
  const int w = tid & 31;
  const int lt = tid >> 5;       // 0..7 == p
  const int t0i = th * 32 + lt;  // t = t0i + 8q
  const int hbase = th ? (192 + t0i) : t0i;
  float stc[4], sts[4], pcq[4], psq[4], ar[4], ai[4];
#pragma unroll
  for (int q = 0; q < 4; ++q) {
    sincosf(-TWO_PI * (float)(hbase + 8 * q) / 256.0f, &sts[q], &stc[q]);
    pcq[q] = 1.f; psq[q] = 0.f; ar[q] = 0.f; ai[q] = 0.f;
  }
  const float2* sp = zs + lt * 1024 + w;  // S row y1+32*lt -> + y1*32
  for (int y1 = 0; y1 < 32; ++y1) {
    const float2 v = sp[y1 * 32];
#pragma unroll
    for (int q = 0; q < 4; ++q) {
      ar[q] = fmaf(v.x, pcq[q], fmaf(-v.y, psq[q], ar[q]));
      ai[q] = fmaf(v.x, psq[q], fmaf( v.y, pcq[q], ai[q]));
      const float tn = fmaf(pcq[q], stc[q], -psq[q] * sts[q]);
      psq[q] = fmaf(pcq[q], sts[q], psq[q] * stc[q]);
      pcq[q] = tn;
    }
  }
  float2* dst = z2 + (long)bc * 2048 + t0i * 32 + w;
#pragma unroll
  for (int q = 0; q < 4; ++q) dst[q * 256] = make_float2(ar[q], ai[q]);
}

// kC (R5 proven): 2048 blocks; block = 8 modes (same b,t; 8 w).
__global__ __launch_bounds__(256) void kC(const float2* __restrict__ z2,
                                          const float2* __restrict__ kp,
                                          float2* __restrict__ g) {
  __shared__ float2 z2s[8 * 33];
  __shared__ float2 fk[8 * 33];
  __shared__ float2 tw[32];
  const int tid = threadIdx.x;
  if (tid < 32) {
    float s, c;
    sincosf(-TWO_PI * (float)tid / 32.0f, &s, &c);
    tw[tid] = make_float2(c, s);
  }
  const int m0 = blockIdx.x * 8;
  const int b = m0 >> 11;
  const int twi = m0 & 2047;
  const int t = twi >> 5;
  const int w0 = twi & 31;
  const int s_ = t >> 5, tm = t & 31;
  {
    const int ci = tid >> 3, wj = tid & 7;
    z2s[wj * 33 + ci] = z2[((long)(b * 32 + ci)) * 2048 + t * 32 + w0 + wj];
  }
  __syncthreads();
  const int m = tid & 7;
  {
    const int cf = tid >> 3;
    float fr = 0, fi = 0;
    int i0 = 0;
#pragma unroll 8
    for (int ci = 0; ci < 32; ++ci) {
      const float2 z = z2s[m * 33 + ci];
      const float2 t0 = tw[i0]; i0 = (i0 + cf) & 31;
      fr = fmaf(z.x, t0.x, fmaf(-z.y, t0.y, fr));
      fi = fmaf(z.x, t0.y, fmaf( z.y, t0.x, fi));
    }
    const float2 k0 = kp[((s_ * 32 + cf) * 32 + tm) * 32 + w0 + m];
    fk[m * 33 + cf] = make_float2(fr * k0.x - fi * k0.y, fr * k0.y + fi * k0.x);
  }
  __syncthreads();
  {
    const int co = tid >> 3;
    float gr = 0, gi = 0;
    int i0 = 0;
#pragma unroll 8
    for (int cf = 0; cf < 32; ++cf) {
      const float2 f = fk[m * 33 + cf];
      const float2 t0 = tw[i0]; i0 = (i0 + co) & 31;
      gr = fmaf(f.x, t0.x, fmaf( f.y, t0.y, gr));
      gi = fmaf(f.y, t0.x, fmaf(-f.x, t0.y, gi));
    }
    const float SC = 1.0f / 8192.0f;
    g[((long)(b * 32 + co)) * 2048 + t * 32 + w0 + m] = make_float2(gr * SC, gi * SC);
  }
}

// kDE2: fused kD1+phase2+kE per bc. 512 blocks = (bc, yh); 512 thr.
// Phase a: thread pair e<2 = (y1=(tid+512e)>>5, w=tid&31): U[p<8] in regs,
//   64-t loop over gs, phasor step e^{+2pi i y1/256}, reset at t=32.
// Per yq (4 per block): phase b: T = sum_p U[p] e^{+2pi i p yq/8} -> tst;
//   phase c: kE x-DFT for 32 rows (rh=tid>>5 -> rows 2rh,2rh+1; 4 x each).
__global__ __launch_bounds__(512) void kDE2(const float2* __restrict__ g,
                                            float* __restrict__ out) {
  __shared__ float2 gs[2048];      // 16 KB
  __shared__ float2 tst[32 * 34];  // 8.5 KB
  const int tid = threadIdx.x;
  const int bc = blockIdx.x >> 1, yh = blockIdx.x & 1;
  {
    const float4* s4 = (const float4*)(g + (long)bc * 2048);
    float4* d4 = (float4*)gs;
    for (int i = tid; i < 1024; i += 512) d4[i] = s4[i];
  }
  __syncthreads();
  const int w = tid & 31;
  float Ur[2][8], Ui[2][8];
#pragma unroll
  for (int e = 0; e < 2; ++e) {
    const int y1 = (tid + (e << 9)) >> 5;  // 0..31
#pragma unroll
    for (int p = 0; p < 8; ++p) { Ur[e][p] = 0.f; Ui[e][p] = 0.f; }
    float s1, c1;
    sincosf(TWO_PI * (float)y1 / 256.0f, &s1, &c1);
    float pc = 1.f, ps = 0.f;
#pragma unroll
    for (int t = 0; t < 64; ++t) {
      if (t == 32) {
        float s2, c2;
        sincosf(TWO_PI * (float)((224 * y1) & 255) / 256.0f, &s2, &c2);
        pc = c2; ps = s2;
      }
      const float2 v = gs[t * 32 + w];
      const int k = t & 7;
      Ur[e][k] = fmaf(v.x, pc, fmaf(-v.y, ps, Ur[e][k]));
      Ui[e][k] = fmaf(v.x, ps, fmaf( v.y, pc, Ui[e][k]));
      const float tn = fmaf(pc, c1, -ps * s1);
      ps = fmaf(pc, s1, ps * c1);
      pc = tn;
    }
  }
  // hoisted kE constants
  const int xq = tid & 31;
  const int rh = tid >> 5;  // 0..15 -> rows 2rh, 2rh+1
  float sb, cb;
  sincosf(TWO_PI * (float)xq / 256.0f, &sb, &cb);
  const float RT = 0.70710678118654752440f;
  const float stc1 = RT * (cb - sb), sts1 = RT * (cb + sb);
  const float stcx[4] = {cb, stc1, -sb, -sts1};
  const float stsx[4] = {sb, sts1, cb, stc1};
  const long rb0 = (long)bc * 256;
#pragma unroll
  for (int yql = 0; yql < 4; ++yql) {
    const int yq = yh * 4 + yql;
    {  // phase b
      float sqv, cqv;
      sincosf(TWO_PI * (float)yq / 8.0f, &sqv, &cqv);
#pragma unroll
      for (int e = 0; e < 2; ++e) {
        const int y1 = (tid + (e << 9)) >> 5;
        float tr = 0.f, ti = 0.f, qc = 1.f, qs = 0.f;
#pragma unroll
        for (int p = 0; p < 8; ++p) {
          tr = fmaf(Ur[e][p], qc, fmaf(-Ui[e][p], qs, tr));
          ti = fmaf(Ur[e][p], qs, fmaf( Ui[e][p], qc, ti));
          const float tn = fmaf(qc, cqv, -qs * sqv);
          qs = fmaf(qc, sqv, qs * cqv);
          qc = tn;
        }
        const float sc = w ? (2.0f / 256.0f) : (1.0f / 256.0f);
        tst[w * 34 + y1] = make_float2(tr * sc, ti * sc);
      }
    }
    __syncthreads();
    {  // phase c: kE for rows rb0 + yq*32 .. +31
      float C[4][2], S[4][2];
#pragma unroll
      for (int m = 0; m < 4; ++m) {
        C[m][0] = 0.f; C[m][1] = 0.f; S[m][0] = 0.f; S[m][1] = 0.f;
      }
      float pcx[4] = {1.f, 1.f, 1.f, 1.f}, psx[4] = {0.f, 0.f, 0.f, 0.f};
      const float* tbse = (const float*)tst + rh * 4;
#pragma unroll 2
      for (int w2 = 0; w2 < 32; ++w2) {
        const float4 q0 = *(const float4*)(tbse + w2 * 68);  // rows 2rh, 2rh+1
#pragma unroll
        for (int m = 0; m < 4; ++m) {
          C[m][0] = fmaf(q0.x, pcx[m], C[m][0]);
          S[m][0] = fmaf(q0.y, psx[m], S[m][0]);
          C[m][1] = fmaf(q0.z, pcx[m], C[m][1]);
          S[m][1] = fmaf(q0.w, psx[m], S[m][1]);
          const float tn = fmaf(pcx[m], stcx[m], -psx[m] * stsx[m]);
          psx[m] = fmaf(pcx[m], stsx[m], psx[m] * stcx[m]);
          pcx[m] = tn;
        }
      }
      const long rbase = rb0 + yq * 32;
#pragma unroll
      for (int m = 0; m < 4; ++m) {
        const int xx = xq + 32 * m;
#pragma unroll
        for (int j = 0; j < 2; ++j) {
          const long row = rbase + rh * 2 + j;
          out[row * 256 + xx] = C[m][j] - S[m][j];
          out[row * 256 + ((256 - xx) & 255)] = C[m][j] + S[m][j];
        }
      }
      if (tid < 32) {  // column x=128: sum (-1)^w a_w
        float ae = 0.f, ao = 0.f;
#pragma unroll
        for (int k = 0; k < 16; ++k) {
          ae += tst[(2 * k) * 34 + tid].x;
          ao += tst[(2 * k + 1) * 34 + tid].x;
        }
        out[(rbase + tid) * 256 + 128] = ae - ao;
      }
    }
    __syncthreads();
  }
}

extern "C" void kernel_launch(void* const* d_in, const int* in_sizes, int n_in,
                              void* d_out, int out_size, void* d_ws, size_t ws_size,
                              hipStream_t stream) {
  const float* x = (const float*)d_in[0];
  const float* kin = (const float*)d_in[1];
  const float* rp = (const float*)d_in[2];
  float* out = (float*)d_out;
  char* ws = (char*)d_ws;

  float2* z1 = (float2*)(ws);                   // 0..16M (kA w, kB r)
  float2* z2 = (float2*)(ws + (16ull << 20));   // 16..24M (kB w, kC r)
  float2* kp = (float2*)(ws + (24ull << 20));   // 24..24.5M (kP w, kC r)
  float2* g  = (float2*)(ws);                   // 0..4M (kC w, kDE2 r; over dead z1)

  kP<<<256, 256, 0, stream>>>(kin, rp, kp);
  kA<<<2048, 256, 0, stream>>>(x, z1);
  kB<<<512, 256, 0, stream>>>(z1, z2);
  kC<<<2048, 256, 0, stream>>>(z2, kp, g);
  kDE2<<<512, 512, 0, stream>>>(g, out);
}

// Round 10
// 185.221 us; speedup vs baseline: 1.4134x; 1.0677x over previous
//
#include <hip/hip_runtime.h>
#include <math.h>

// FourierKNOConv2d: x[8,32,256,256] f32, kernel[2,1,32,32,32,2] f32, r scalar.
// out[8,32,256,256] f32.
//   kP:   Kp = (kr + i ki)^r                                [2,32,32,32] c64
//   kX:   Bf[64x256] f16, pre-fragmented for mfma 16x16x32:
//         B[2w+cs][x] = cs ? -sc_w sin(2pi w x/256) : sc_w cos(2pi w x/256),
//         sc_w=(w?2:1)/256. Layout: [(n*2+kk)][lane][i<8] halves.
//   kA:   Z1[row,w] = sum_x X[row,x] e^{-2pi i w x/256}, w<32 (LDS FFT8 + sum)
//   kB:   fused per-bc: z1[bc]->LDS, FFT8 over y2 in LDS, then
//         Z2[bc,t,w] = sum_{y1} S[y1,t&7,w] e^{-2pi i h(t) y1/256}
//   kC:   G = idft32_ch( dft32_ch(z2) * Kp ) / 8192
//   kDE2: per (bc,yh): stage g[bc]->LDS;
//         phase a: U[p<8] per (y1,w) in regs (64-t loop);
//         per yq: phase b: T[y1,w] = sum_p U[p] e^{+2pi i p yq/8} -> tst2 (f16)
//                 phase c: out[32x256] = T(32x64) x Bf(64x256) via MFMA f16
//                 (mirror symmetry no longer needed — B covers all 256 cols)
// ws map (25.1 MB): z1 @0..16M, z2 @16..24M, kp @24..24.5M, Bf @25..25.04M,
//   g @0..4M (over dead z1)

#define TWO_PI 6.28318530717958647692f

typedef _Float16 half8 __attribute__((ext_vector_type(8)));
typedef float float4v __attribute__((ext_vector_type(4)));

__global__ __launch_bounds__(256) void kP(const float* __restrict__ kin,
                                          const float* __restrict__ rp,
                                          float2* __restrict__ kp) {
  const int i = blockIdx.x * 256 + threadIdx.x;  // < 65536
  const float r = rp[0];
  const float kr = kin[2 * i], ki = kin[2 * i + 1];
  const float m2 = fmaf(kr, kr, ki * ki);
  float2 o = make_float2(0.f, 0.f);
  if (m2 > 0.f) {
    const float lm = 0.5f * logf(m2);
    const float ang = atan2f(ki, kr);
    const float mag = expf(r * lm);
    float s, c;
    sincosf(r * ang, &s, &c);
    o = make_float2(mag * c, mag * s);
  }
  kp[i] = o;
}

// kX: build Bf (16384 halves = 32 KB). 32 blocks x 256 thr x 2 halves.
// flat = ((n*2+kk)*64 + lane)*8 + i ; k = kk*32 + (lane>>4)*8 + i ;
// w = k>>1, cs = k&1, x = n*16 + (lane&15). Exact integer-mod angles.
__global__ __launch_bounds__(256) void kX(_Float16* __restrict__ Bf) {
  const int f0 = (blockIdx.x * 256 + threadIdx.x) * 2;
#pragma unroll
  for (int u = 0; u < 2; ++u) {
    const int f = f0 + u;
    const int i = f & 7;
    const int lane = (f >> 3) & 63;
    const int kk = (f >> 9) & 1;
    const int n = f >> 10;
    const int k = kk * 32 + ((lane >> 4) << 3) + i;
    const int w = k >> 1, cs = k & 1;
    const int xc = n * 16 + (lane & 15);
    const float sc = (w ? 2.0f : 1.0f) / 256.0f;
    float s, c;
    sincosf(TWO_PI * (float)((w * xc) & 255) / 256.0f, &s, &c);
    Bf[f] = (_Float16)(cs ? (-s * sc) : (c * sc));
  }
}

// kA (R5 proven): 2048 blocks; block = 32 rows. LDS 32 KB, rotate-swizzle
// idx(x,r) = x*32 + ((r + 4x) & 31). Pass2: in-LDS real FFT8 over x2.
// Pass3: 32-term phasor sum with precomputed swizzled pointers.
__global__ __launch_bounds__(256) void kA(const float* __restrict__ x,
                                          float2* __restrict__ z1) {
  __shared__ float xs[8192];  // 32 KB
  const int tid = threadIdx.x;
  const long row0 = (long)blockIdx.x * 32;
  const float* xg = x + row0 * 256;
  {
    const int xl = tid & 31, rq = tid >> 5;
    const float* xgr = xg + rq * 4 * 256 + xl;
#pragma unroll
    for (int cb = 0; cb < 8; ++cb) {
      const int xc = xl + 32 * cb;
      const float4 v = make_float4(xgr[32 * cb], xgr[32 * cb + 256],
                                   xgr[32 * cb + 512], xgr[32 * cb + 768]);
      *(float4*)(xs + xc * 32 + 4 * ((rq + xc) & 7)) = v;
    }
  }
  __syncthreads();
  const float RT = 0.70710678118654752440f;
#pragma unroll
  for (int k = 0; k < 4; ++k) {
    const int i = tid + (k << 8);
    const int x1 = i >> 5, r = i & 31;
    float* base = xs + x1 * 32 + ((r + 4 * x1) & 31);
    const float a0 = base[0],        a1 = base[1024],     a2 = base[2048];
    const float a3 = base[3 * 1024], a4 = base[4 * 1024], a5 = base[5 * 1024];
    const float a6 = base[6 * 1024], a7 = base[7 * 1024];
    const float t0 = a0 + a4, t1 = a0 - a4, t2 = a2 + a6, t3 = a2 - a6;
    const float u0 = a1 + a5, u1 = a1 - a5, u2 = a3 + a7, u3 = a3 - a7;
    const float E0 = t0 + t2, O0 = u0 + u2;
    const float d1 = RT * (u1 - u3), d2 = RT * (u1 + u3);
    base[0]        = E0 + O0;
    base[1024]     = E0 - O0;
    base[2 * 1024] = t1 + d1;
    base[3 * 1024] = -(t3 + d2);
    base[4 * 1024] = t0 - t2;
    base[5 * 1024] = -(u0 - u2);
    base[6 * 1024] = t1 - d1;
    base[7 * 1024] = t3 - d2;
  }
  __syncthreads();
  const int w = tid & 31;
  const int r0 = (tid >> 5) << 2;
  const int p = w & 7;
  int pr, pi;
  float si;
  if (p == 0)      { pr = 0;           pi = 0;      si = 0.f; }
  else if (p == 4) { pr = 1;           pi = 1;      si = 0.f; }
  else if (p < 4)  { pr = 2 * p;       pi = pr + 1; si = 1.f; }
  else             { pr = 2 * (8 - p); pi = pr + 1; si = -1.f; }
  const char* ur = (const char*)xs + pr * 4096;
  const char* ui = (const char*)xs + pi * 4096;
  const char* urp[8];
  const char* uip[8];
#pragma unroll
  for (int j = 0; j < 8; ++j) {
    const int off = 4 * ((r0 + 4 * j) & 31) + 128 * j;
    urp[j] = ur + off;
    uip[j] = ui + off;
  }
  float s1, c1;
  sincosf(-TWO_PI * (float)w / 256.0f, &s1, &c1);
  float pc = 1.f, ps = 0.f;
  float Cr0 = 0, Cr1 = 0, Cr2 = 0, Cr3 = 0;
  float Ci0 = 0, Ci1 = 0, Ci2 = 0, Ci3 = 0;
#pragma unroll
  for (int bq = 0; bq < 4; ++bq) {
#pragma unroll
    for (int j = 0; j < 8; ++j) {
      const float4 Fr = *(const float4*)(urp[j] + bq * 1024);
      const float4 Fi = *(const float4*)(uip[j] + bq * 1024);
      const float qs = si * ps, qc = si * pc;
      Cr0 = fmaf(Fr.x, pc, fmaf(-Fi.x, qs, Cr0));
      Ci0 = fmaf(Fr.x, ps, fmaf( Fi.x, qc, Ci0));
      Cr1 = fmaf(Fr.y, pc, fmaf(-Fi.y, qs, Cr1));
      Ci1 = fmaf(Fr.y, ps, fmaf( Fi.y, qc, Ci1));
      Cr2 = fmaf(Fr.z, pc, fmaf(-Fi.z, qs, Cr2));
      Ci2 = fmaf(Fr.z, ps, fmaf( Fi.z, qc, Ci2));
      Cr3 = fmaf(Fr.w, pc, fmaf(-Fi.w, qs, Cr3));
      Ci3 = fmaf(Fr.w, ps, fmaf( Fi.w, qc, Ci3));
      const float tn = fmaf(pc, c1, -ps * s1);
      ps = fmaf(pc, s1, ps * c1);
      pc = tn;
    }
  }
  float2* o = z1 + (row0 + r0) * 32 + w;
  o[0]  = make_float2(Cr0, Ci0);
  o[32] = make_float2(Cr1, Ci1);
  o[64] = make_float2(Cr2, Ci2);
  o[96] = make_float2(Cr3, Ci3);
}

// kB: fused kB1+kB2 per bc. 512 blocks = (bc, th); 256 thr; 64 KB LDS.
__global__ __launch_bounds__(256) void kB(const float2* __restrict__ z1,
                                          float2* __restrict__ z2) {
  __shared__ float2 zs[8192];  // 64 KB
  const int tid = threadIdx.x;
  const int bc = blockIdx.x >> 1, th = blockIdx.x & 1;
  {
    const float4* s4 = (const float4*)(z1 + (long)bc * 8192);
    float4* d4 = (float4*)zs;
    for (int i = tid; i < 4096; i += 256) d4[i] = s4[i];
  }
  __syncthreads();
  const float RT = 0.70710678118654752440f;
#pragma unroll
  for (int e = 0; e < 4; ++e) {
    float2* base = zs + tid + (e << 8);  // cell (y1,w), + j*1024 per y2
    float2 a[8];
#pragma unroll
    for (int j = 0; j < 8; ++j) a[j] = base[j * 1024];
    float2 t0 = make_float2(a[0].x + a[4].x, a[0].y + a[4].y);
    float2 t1 = make_float2(a[0].x - a[4].x, a[0].y - a[4].y);
    float2 t2 = make_float2(a[2].x + a[6].x, a[2].y + a[6].y);
    float2 t3 = make_float2(a[2].x - a[6].x, a[2].y - a[6].y);
    const float2 E0 = make_float2(t0.x + t2.x, t0.y + t2.y);
    const float2 E2 = make_float2(t0.x - t2.x, t0.y - t2.y);
    const float2 E1 = make_float2(t1.x + t3.y, t1.y - t3.x);  // t1 - i*t3
    const float2 E3 = make_float2(t1.x - t3.y, t1.y + t3.x);  // t1 + i*t3
    t0 = make_float2(a[1].x + a[5].x, a[1].y + a[5].y);
    t1 = make_float2(a[1].x - a[5].x, a[1].y - a[5].y);
    t2 = make_float2(a[3].x + a[7].x, a[3].y + a[7].y);
    t3 = make_float2(a[3].x - a[7].x, a[3].y - a[7].y);
    const float2 O0 = make_float2(t0.x + t2.x, t0.y + t2.y);
    const float2 O2 = make_float2(t0.x - t2.x, t0.y - t2.y);
    const float2 O1 = make_float2(t1.x + t3.y, t1.y - t3.x);
    const float2 O3 = make_float2(t1.x - t3.y, t1.y + t3.x);
    const float2 B0 = O0;
    const float2 B1 = make_float2(RT * (O1.x + O1.y), RT * (O1.y - O1.x));
    const float2 B2 = make_float2(O2.y, -O2.x);  // -i*O2
    const float2 B3 = make_float2(RT * (O3.y - O3.x), -RT * (O3.x + O3.y));
    base[0]        = make_float2(E0.x + B0.x, E0.y + B0.y);
    base[1 * 1024] = make_float2(E1.x + B1.x, E1.y + B1.y);
    base[2 * 1024] = make_float2(E2.x + B2.x, E2.y + B2.y);
    base[3 * 1024] = make_float2(E3.x + B3.x, E3.y + B3.y);
    base[4 * 1024] = make_float2(E0.x - B0.x, E0.y - B0.y);
    base[5 * 1024] = make_float2(E1.x - B1.x, E1.y - B1.y);
    base[6 * 1024] = make_float2(E2.x - B2.x, E2.y - B2.y);
    base[7 * 1024] = make_float2(E3.x - B3.x, E3.y - B3.y);
  }
  __syncthreads();
  const int w = tid & 31;
  const int lt = tid >> 5;       // 0..7 == p
  const int t0i = th * 32 + lt;  // t = t0i + 8q
  const int hbase = th ? (192 + t0i) : t0i;
  float stc[4], sts[4], pcq[4], psq[4], ar[4], ai[4];
#pragma unroll
  for (int q = 0; q < 4; ++q) {
    sincosf(-TWO_PI * (float)(hbase + 8 * q) / 256.0f, &sts[q], &stc[q]);
    pcq[q] = 1.f; psq[q] = 0.f; ar[q] = 0.f; ai[q] = 0.f;
  }
  const float2* sp = zs + lt * 1024 + w;  // S row y1+32*lt -> + y1*32
  for (int y1 = 0; y1 < 32; ++y1) {
    const float2 v = sp[y1 * 32];
#pragma unroll
    for (int q = 0; q < 4; ++q) {
      ar[q] = fmaf(v.x, pcq[q], fmaf(-v.y, psq[q], ar[q]));
      ai[q] = fmaf(v.x, psq[q], fmaf( v.y, pcq[q], ai[q]));
      const float tn = fmaf(pcq[q], stc[q], -psq[q] * sts[q]);
      psq[q] = fmaf(pcq[q], sts[q], psq[q] * stc[q]);
      pcq[q] = tn;
    }
  }
  float2* dst = z2 + (long)bc * 2048 + t0i * 32 + w;
#pragma unroll
  for (int q = 0; q < 4; ++q) dst[q * 256] = make_float2(ar[q], ai[q]);
}

// kC (R5 proven): 2048 blocks; block = 8 modes (same b,t; 8 w).
__global__ __launch_bounds__(256) void kC(const float2* __restrict__ z2,
                                          const float2* __restrict__ kp,
                                          float2* __restrict__ g) {
  __shared__ float2 z2s[8 * 33];
  __shared__ float2 fk[8 * 33];
  __shared__ float2 tw[32];
  const int tid = threadIdx.x;
  if (tid < 32) {
    float s, c;
    sincosf(-TWO_PI * (float)tid / 32.0f, &s, &c);
    tw[tid] = make_float2(c, s);
  }
  const int m0 = blockIdx.x * 8;
  const int b = m0 >> 11;
  const int twi = m0 & 2047;
  const int t = twi >> 5;
  const int w0 = twi & 31;
  const int s_ = t >> 5, tm = t & 31;
  {
    const int ci = tid >> 3, wj = tid & 7;
    z2s[wj * 33 + ci] = z2[((long)(b * 32 + ci)) * 2048 + t * 32 + w0 + wj];
  }
  __syncthreads();
  const int m = tid & 7;
  {
    const int cf = tid >> 3;
    float fr = 0, fi = 0;
    int i0 = 0;
#pragma unroll 8
    for (int ci = 0; ci < 32; ++ci) {
      const float2 z = z2s[m * 33 + ci];
      const float2 t0 = tw[i0]; i0 = (i0 + cf) & 31;
      fr = fmaf(z.x, t0.x, fmaf(-z.y, t0.y, fr));
      fi = fmaf(z.x, t0.y, fmaf( z.y, t0.x, fi));
    }
    const float2 k0 = kp[((s_ * 32 + cf) * 32 + tm) * 32 + w0 + m];
    fk[m * 33 + cf] = make_float2(fr * k0.x - fi * k0.y, fr * k0.y + fi * k0.x);
  }
  __syncthreads();
  {
    const int co = tid >> 3;
    float gr = 0, gi = 0;
    int i0 = 0;
#pragma unroll 8
    for (int cf = 0; cf < 32; ++cf) {
      const float2 f = fk[m * 33 + cf];
      const float2 t0 = tw[i0]; i0 = (i0 + co) & 31;
      gr = fmaf(f.x, t0.x, fmaf( f.y, t0.y, gr));
      gi = fmaf(f.y, t0.x, fmaf(-f.x, t0.y, gi));
    }
    const float SC = 1.0f / 8192.0f;
    g[((long)(b * 32 + co)) * 2048 + t * 32 + w0 + m] = make_float2(gr * SC, gi * SC);
  }
}

// kDE2: 512 blocks = (bc, yh); 512 thr. Phase a unchanged (R9). Phase b emits
// raw (Tr,Ti) as f16 into tst2[y1][2w..]. Phase c: MFMA f16 16x16x32:
// out[32x256] = A(32x64) x B(64x256). A-frag: lane holds row=lane&15,
// k = kk*32 + (lane>>4)*8 + i (AMD-documented A layout; any consistent A/B
// k-permutation cancels). D: col=lane&15, row=(lane>>4)*4+j (m89-verified).
// Wave wv owns n-tiles {2wv, 2wv+1}; B-frags in regs for whole kernel.
__global__ __launch_bounds__(512) void kDE2(const float2* __restrict__ g,
                                            const _Float16* __restrict__ Bf,
                                            float* __restrict__ out) {
  __shared__ float2 gs[2048];          // 16 KB
  __shared__ _Float16 tst2[32 * 68];   // 4.25 KB, row stride 68 halves
  const int tid = threadIdx.x;
  const int bc = blockIdx.x >> 1, yh = blockIdx.x & 1;
  const int lane = tid & 63, l15 = lane & 15, lg = lane >> 4;
  uint4 bfr[2][2];  // B-frags [nn][kk], constant across yq and bc
#pragma unroll
  for (int nn = 0; nn < 2; ++nn)
#pragma unroll
    for (int kk = 0; kk < 2; ++kk) {
      const int n = 2 * (tid >> 6) + nn;
      bfr[nn][kk] = *(const uint4*)(Bf + (((n * 2 + kk) * 64) + lane) * 8);
    }
  {
    const float4* s4 = (const float4*)(g + (long)bc * 2048);
    float4* d4 = (float4*)gs;
    for (int i = tid; i < 1024; i += 512) d4[i] = s4[i];
  }
  __syncthreads();
  const int w = tid & 31;
  float Ur[2][8], Ui[2][8];
#pragma unroll
  for (int e = 0; e < 2; ++e) {
    const int y1 = (tid + (e << 9)) >> 5;  // 0..31
#pragma unroll
    for (int p = 0; p < 8; ++p) { Ur[e][p] = 0.f; Ui[e][p] = 0.f; }
    float s1, c1;
    sincosf(TWO_PI * (float)y1 / 256.0f, &s1, &c1);
    float pc = 1.f, ps = 0.f;
#pragma unroll
    for (int t = 0; t < 64; ++t) {
      if (t == 32) {
        float s2, c2;
        sincosf(TWO_PI * (float)((224 * y1) & 255) / 256.0f, &s2, &c2);
        pc = c2; ps = s2;
      }
      const float2 v = gs[t * 32 + w];
      const int k = t & 7;
      Ur[e][k] = fmaf(v.x, pc, fmaf(-v.y, ps, Ur[e][k]));
      Ui[e][k] = fmaf(v.x, ps, fmaf( v.y, pc, Ui[e][k]));
      const float tn = fmaf(pc, c1, -ps * s1);
      ps = fmaf(pc, s1, ps * c1);
      pc = tn;
    }
  }
  const long rb0 = (long)bc * 256;
#pragma unroll
  for (int yql = 0; yql < 4; ++yql) {
    const int yq = yh * 4 + yql;
    {  // phase b: T = sum_p U[p] e^{+2pi i p yq/8} -> tst2 (raw f16, no scale)
      float sqv, cqv;
      sincosf(TWO_PI * (float)yq / 8.0f, &sqv, &cqv);
#pragma unroll
      for (int e = 0; e < 2; ++e) {
        const int y1 = (tid + (e << 9)) >> 5;
        float tr = 0.f, ti = 0.f, qc = 1.f, qs = 0.f;
#pragma unroll
        for (int p = 0; p < 8; ++p) {
          tr = fmaf(Ur[e][p], qc, fmaf(-Ui[e][p], qs, tr));
          ti = fmaf(Ur[e][p], qs, fmaf( Ui[e][p], qc, ti));
          const float tn = fmaf(qc, cqv, -qs * sqv);
          qs = fmaf(qc, sqv, qs * cqv);
          qc = tn;
        }
        union { unsigned int u; _Float16 h[2]; } hu;
        hu.h[0] = (_Float16)tr;
        hu.h[1] = (_Float16)ti;
        *(unsigned int*)&tst2[y1 * 68 + 2 * w] = hu.u;
      }
    }
    __syncthreads();
    {  // phase c: MFMA
      half8 afr[2][2];  // A-frags [rt][kk]
#pragma unroll
      for (int rt = 0; rt < 2; ++rt)
#pragma unroll
        for (int kk = 0; kk < 2; ++kk) {
          const _Float16* ap = tst2 + (rt * 16 + l15) * 68 + kk * 32 + lg * 8;
          const uint2 lo = *(const uint2*)ap;
          const uint2 hi = *(const uint2*)(ap + 4);
          uint4 u4;
          u4.x = lo.x; u4.y = lo.y; u4.z = hi.x; u4.w = hi.y;
          afr[rt][kk] = __builtin_bit_cast(half8, u4);
        }
      const long rbase = rb0 + yq * 32;
#pragma unroll
      for (int rt = 0; rt < 2; ++rt)
#pragma unroll
        for (int nn = 0; nn < 2; ++nn) {
          float4v acc = {0.f, 0.f, 0.f, 0.f};
          acc = __builtin_amdgcn_mfma_f32_16x16x32_f16(
              afr[rt][0], __builtin_bit_cast(half8, bfr[nn][0]), acc, 0, 0, 0);
          acc = __builtin_amdgcn_mfma_f32_16x16x32_f16(
              afr[rt][1], __builtin_bit_cast(half8, bfr[nn][1]), acc, 0, 0, 0);
          const int n = 2 * (tid >> 6) + nn;
          const int col = n * 16 + l15;
          const long r0w = rbase + rt * 16 + lg * 4;
          out[(r0w + 0) * 256 + col] = acc[0];
          out[(r0w + 1) * 256 + col] = acc[1];
          out[(r0w + 2) * 256 + col] = acc[2];
          out[(r0w + 3) * 256 + col] = acc[3];
        }
    }
    __syncthreads();
  }
}

extern "C" void kernel_launch(void* const* d_in, const int* in_sizes, int n_in,
                              void* d_out, int out_size, void* d_ws, size_t ws_size,
                              hipStream_t stream) {
  const float* x = (const float*)d_in[0];
  const float* kin = (const float*)d_in[1];
  const float* rp = (const float*)d_in[2];
  float* out = (float*)d_out;
  char* ws = (char*)d_ws;

  float2* z1 = (float2*)(ws);                    // 0..16M (kA w, kB r)
  float2* z2 = (float2*)(ws + (16ull << 20));    // 16..24M (kB w, kC r)
  float2* kp = (float2*)(ws + (24ull << 20));    // 24..24.5M (kP w, kC r)
  _Float16* Bf = (_Float16*)(ws + (25ull << 20));// 25..25.04M (kX w, kDE2 r)
  float2* g  = (float2*)(ws);                    // 0..4M (kC w, kDE2 r)

  kP<<<256, 256, 0, stream>>>(kin, rp, kp);
  kX<<<32, 256, 0, stream>>>(Bf);
  kA<<<2048, 256, 0, stream>>>(x, z1);
  kB<<<512, 256, 0, stream>>>(z1, z2);
  kC<<<2048, 256, 0, stream>>>(z2, kp, g);
  kDE2<<<512, 512, 0, stream>>>(g, Bf, out);
}

// Round 11
// 182.840 us; speedup vs baseline: 1.4318x; 1.0130x over previous
//
#include <hip/hip_runtime.h>
#include <math.h>

// FourierKNOConv2d: x[8,32,256,256] f32, kernel[2,1,32,32,32,2] f32, r scalar.
// out[8,32,256,256] f32.
//   kPX:  (fused) Kp = (kr+i ki)^r  [2,32,32,32] c64;  Bf[64x256] f16 DFT
//         matrix pre-fragmented for mfma 16x16x32 (B[2w+cs][x], scale folded).
//   kA:   Z1[row,w] = sum_x X[row,x] e^{-2pi i w x/256}, w<32 (LDS FFT8 + sum)
//   kB:   fused per-bc: z1[bc]->LDS, FFT8 over y2 in LDS, then
//         Z2[bc,t,w] = sum_{y1} S[y1,t&7,w] e^{-2pi i h(t) y1/256}
//   kC:   G = idft32_ch( dft32_ch(z2) * Kp ) / 8192
//   kDE2: per (bc,yh): stage g[bc]->LDS; phase a: U[p<8] per (y1,w) in regs;
//         per yq: phase b: T -> tst2 (f16); phase c: MFMA f16 out-tile ->
//         ot LDS (stride 260) -> coalesced float4 row writes (fixes R10's
//         1.8x write amplification from scattered 64B D-fragment stores).
// ws map (25.1 MB): z1 @0..16M, z2 @16..24M, kp @24..24.5M, Bf @25..25.04M,
//   g @0..4M (over dead z1)

#define TWO_PI 6.28318530717958647692f

typedef _Float16 half8 __attribute__((ext_vector_type(8)));
typedef float float4v __attribute__((ext_vector_type(4)));

// kPX: blocks 0..255 -> kP (65536 kernel powers); blocks 256..287 -> kX
// (Bf, 16384 halves; flat = ((n*2+kk)*64+lane)*8+i, k = kk*32+(lane>>4)*8+i,
// w = k>>1, cs = k&1, x = n*16+(lane&15); exact integer-mod angles).
__global__ __launch_bounds__(256) void kPX(const float* __restrict__ kin,
                                           const float* __restrict__ rp,
                                           float2* __restrict__ kp,
                                           _Float16* __restrict__ Bf) {
  const int tid = threadIdx.x;
  if (blockIdx.x < 256) {
    const int i = blockIdx.x * 256 + tid;  // < 65536
    const float r = rp[0];
    const float kr = kin[2 * i], ki = kin[2 * i + 1];
    const float m2 = fmaf(kr, kr, ki * ki);
    float2 o = make_float2(0.f, 0.f);
    if (m2 > 0.f) {
      const float lm = 0.5f * logf(m2);
      const float ang = atan2f(ki, kr);
      const float mag = expf(r * lm);
      float s, c;
      sincosf(r * ang, &s, &c);
      o = make_float2(mag * c, mag * s);
    }
    kp[i] = o;
  } else {
    const int f0 = ((blockIdx.x - 256) * 256 + tid) * 2;
#pragma unroll
    for (int u = 0; u < 2; ++u) {
      const int f = f0 + u;
      const int i = f & 7;
      const int lane = (f >> 3) & 63;
      const int kk = (f >> 9) & 1;
      const int n = f >> 10;
      const int k = kk * 32 + ((lane >> 4) << 3) + i;
      const int w = k >> 1, cs = k & 1;
      const int xc = n * 16 + (lane & 15);
      const float sc = (w ? 2.0f : 1.0f) / 256.0f;
      float s, c;
      sincosf(TWO_PI * (float)((w * xc) & 255) / 256.0f, &s, &c);
      Bf[f] = (_Float16)(cs ? (-s * sc) : (c * sc));
    }
  }
}

// kA (R5 proven): 2048 blocks; block = 32 rows. LDS 32 KB, rotate-swizzle
// idx(x,r) = x*32 + ((r + 4x) & 31). Pass2: in-LDS real FFT8 over x2.
// Pass3: 32-term phasor sum with precomputed swizzled pointers.
__global__ __launch_bounds__(256) void kA(const float* __restrict__ x,
                                          float2* __restrict__ z1) {
  __shared__ float xs[8192];  // 32 KB
  const int tid = threadIdx.x;
  const long row0 = (long)blockIdx.x * 32;
  const float* xg = x + row0 * 256;
  {
    const int xl = tid & 31, rq = tid >> 5;
    const float* xgr = xg + rq * 4 * 256 + xl;
#pragma unroll
    for (int cb = 0; cb < 8; ++cb) {
      const int xc = xl + 32 * cb;
      const float4 v = make_float4(xgr[32 * cb], xgr[32 * cb + 256],
                                   xgr[32 * cb + 512], xgr[32 * cb + 768]);
      *(float4*)(xs + xc * 32 + 4 * ((rq + xc) & 7)) = v;
    }
  }
  __syncthreads();
  const float RT = 0.70710678118654752440f;
#pragma unroll
  for (int k = 0; k < 4; ++k) {
    const int i = tid + (k << 8);
    const int x1 = i >> 5, r = i & 31;
    float* base = xs + x1 * 32 + ((r + 4 * x1) & 31);
    const float a0 = base[0],        a1 = base[1024],     a2 = base[2048];
    const float a3 = base[3 * 1024], a4 = base[4 * 1024], a5 = base[5 * 1024];
    const float a6 = base[6 * 1024], a7 = base[7 * 1024];
    const float t0 = a0 + a4, t1 = a0 - a4, t2 = a2 + a6, t3 = a2 - a6;
    const float u0 = a1 + a5, u1 = a1 - a5, u2 = a3 + a7, u3 = a3 - a7;
    const float E0 = t0 + t2, O0 = u0 + u2;
    const float d1 = RT * (u1 - u3), d2 = RT * (u1 + u3);
    base[0]        = E0 + O0;
    base[1024]     = E0 - O0;
    base[2 * 1024] = t1 + d1;
    base[3 * 1024] = -(t3 + d2);
    base[4 * 1024] = t0 - t2;
    base[5 * 1024] = -(u0 - u2);
    base[6 * 1024] = t1 - d1;
    base[7 * 1024] = t3 - d2;
  }
  __syncthreads();
  const int w = tid & 31;
  const int r0 = (tid >> 5) << 2;
  const int p = w & 7;
  int pr, pi;
  float si;
  if (p == 0)      { pr = 0;           pi = 0;      si = 0.f; }
  else if (p == 4) { pr = 1;           pi = 1;      si = 0.f; }
  else if (p < 4)  { pr = 2 * p;       pi = pr + 1; si = 1.f; }
  else             { pr = 2 * (8 - p); pi = pr + 1; si = -1.f; }
  const char* ur = (const char*)xs + pr * 4096;
  const char* ui = (const char*)xs + pi * 4096;
  const char* urp[8];
  const char* uip[8];
#pragma unroll
  for (int j = 0; j < 8; ++j) {
    const int off = 4 * ((r0 + 4 * j) & 31) + 128 * j;
    urp[j] = ur + off;
    uip[j] = ui + off;
  }
  float s1, c1;
  sincosf(-TWO_PI * (float)w / 256.0f, &s1, &c1);
  float pc = 1.f, ps = 0.f;
  float Cr0 = 0, Cr1 = 0, Cr2 = 0, Cr3 = 0;
  float Ci0 = 0, Ci1 = 0, Ci2 = 0, Ci3 = 0;
#pragma unroll
  for (int bq = 0; bq < 4; ++bq) {
#pragma unroll
    for (int j = 0; j < 8; ++j) {
      const float4 Fr = *(const float4*)(urp[j] + bq * 1024);
      const float4 Fi = *(const float4*)(uip[j] + bq * 1024);
      const float qs = si * ps, qc = si * pc;
      Cr0 = fmaf(Fr.x, pc, fmaf(-Fi.x, qs, Cr0));
      Ci0 = fmaf(Fr.x, ps, fmaf( Fi.x, qc, Ci0));
      Cr1 = fmaf(Fr.y, pc, fmaf(-Fi.y, qs, Cr1));
      Ci1 = fmaf(Fr.y, ps, fmaf( Fi.y, qc, Ci1));
      Cr2 = fmaf(Fr.z, pc, fmaf(-Fi.z, qs, Cr2));
      Ci2 = fmaf(Fr.z, ps, fmaf( Fi.z, qc, Ci2));
      Cr3 = fmaf(Fr.w, pc, fmaf(-Fi.w, qs, Cr3));
      Ci3 = fmaf(Fr.w, ps, fmaf( Fi.w, qc, Ci3));
      const float tn = fmaf(pc, c1, -ps * s1);
      ps = fmaf(pc, s1, ps * c1);
      pc = tn;
    }
  }
  float2* o = z1 + (row0 + r0) * 32 + w;
  o[0]  = make_float2(Cr0, Ci0);
  o[32] = make_float2(Cr1, Ci1);
  o[64] = make_float2(Cr2, Ci2);
  o[96] = make_float2(Cr3, Ci3);
}

// kB: fused kB1+kB2 per bc. 512 blocks = (bc, th); 256 thr; 64 KB LDS.
__global__ __launch_bounds__(256) void kB(const float2* __restrict__ z1,
                                          float2* __restrict__ z2) {
  __shared__ float2 zs[8192];  // 64 KB
  const int tid = threadIdx.x;
  const int bc = blockIdx.x >> 1, th = blockIdx.x & 1;
  {
    const float4* s4 = (const float4*)(z1 + (long)bc * 8192);
    float4* d4 = (float4*)zs;
    for (int i = tid; i < 4096; i += 256) d4[i] = s4[i];
  }
  __syncthreads();
  const float RT = 0.70710678118654752440f;
#pragma unroll
  for (int e = 0; e < 4; ++e) {
    float2* base = zs + tid + (e << 8);  // cell (y1,w), + j*1024 per y2
    float2 a[8];
#pragma unroll
    for (int j = 0; j < 8; ++j) a[j] = base[j * 1024];
    float2 t0 = make_float2(a[0].x + a[4].x, a[0].y + a[4].y);
    float2 t1 = make_float2(a[0].x - a[4].x, a[0].y - a[4].y);
    float2 t2 = make_float2(a[2].x + a[6].x, a[2].y + a[6].y);
    float2 t3 = make_float2(a[2].x - a[6].x, a[2].y - a[6].y);
    const float2 E0 = make_float2(t0.x + t2.x, t0.y + t2.y);
    const float2 E2 = make_float2(t0.x - t2.x, t0.y - t2.y);
    const float2 E1 = make_float2(t1.x + t3.y, t1.y - t3.x);  // t1 - i*t3
    const float2 E3 = make_float2(t1.x - t3.y, t1.y + t3.x);  // t1 + i*t3
    t0 = make_float2(a[1].x + a[5].x, a[1].y + a[5].y);
    t1 = make_float2(a[1].x - a[5].x, a[1].y - a[5].y);
    t2 = make_float2(a[3].x + a[7].x, a[3].y + a[7].y);
    t3 = make_float2(a[3].x - a[7].x, a[3].y - a[7].y);
    const float2 O0 = make_float2(t0.x + t2.x, t0.y + t2.y);
    const float2 O2 = make_float2(t0.x - t2.x, t0.y - t2.y);
    const float2 O1 = make_float2(t1.x + t3.y, t1.y - t3.x);
    const float2 O3 = make_float2(t1.x - t3.y, t1.y + t3.x);
    const float2 B0 = O0;
    const float2 B1 = make_float2(RT * (O1.x + O1.y), RT * (O1.y - O1.x));
    const float2 B2 = make_float2(O2.y, -O2.x);  // -i*O2
    const float2 B3 = make_float2(RT * (O3.y - O3.x), -RT * (O3.x + O3.y));
    base[0]        = make_float2(E0.x + B0.x, E0.y + B0.y);
    base[1 * 1024] = make_float2(E1.x + B1.x, E1.y + B1.y);
    base[2 * 1024] = make_float2(E2.x + B2.x, E2.y + B2.y);
    base[3 * 1024] = make_float2(E3.x + B3.x, E3.y + B3.y);
    base[4 * 1024] = make_float2(E0.x - B0.x, E0.y - B0.y);
    base[5 * 1024] = make_float2(E1.x - B1.x, E1.y - B1.y);
    base[6 * 1024] = make_float2(E2.x - B2.x, E2.y - B2.y);
    base[7 * 1024] = make_float2(E3.x - B3.x, E3.y - B3.y);
  }
  __syncthreads();
  const int w = tid & 31;
  const int lt = tid >> 5;       // 0..7 == p
  const int t0i = th * 32 + lt;  // t = t0i + 8q
  const int hbase = th ? (192 + t0i) : t0i;
  float stc[4], sts[4], pcq[4], psq[4], ar[4], ai[4];
#pragma unroll
  for (int q = 0; q < 4; ++q) {
    sincosf(-TWO_PI * (float)(hbase + 8 * q) / 256.0f, &sts[q], &stc[q]);
    pcq[q] = 1.f; psq[q] = 0.f; ar[q] = 0.f; ai[q] = 0.f;
  }
  const float2* sp = zs + lt * 1024 + w;  // S row y1+32*lt -> + y1*32
  for (int y1 = 0; y1 < 32; ++y1) {
    const float2 v = sp[y1 * 32];
#pragma unroll
    for (int q = 0; q < 4; ++q) {
      ar[q] = fmaf(v.x, pcq[q], fmaf(-v.y, psq[q], ar[q]));
      ai[q] = fmaf(v.x, psq[q], fmaf( v.y, pcq[q], ai[q]));
      const float tn = fmaf(pcq[q], stc[q], -psq[q] * sts[q]);
      psq[q] = fmaf(pcq[q], sts[q], psq[q] * stc[q]);
      pcq[q] = tn;
    }
  }
  float2* dst = z2 + (long)bc * 2048 + t0i * 32 + w;
#pragma unroll
  for (int q = 0; q < 4; ++q) dst[q * 256] = make_float2(ar[q], ai[q]);
}

// kC (R5 proven): 2048 blocks; block = 8 modes (same b,t; 8 w).
__global__ __launch_bounds__(256) void kC(const float2* __restrict__ z2,
                                          const float2* __restrict__ kp,
                                          float2* __restrict__ g) {
  __shared__ float2 z2s[8 * 33];
  __shared__ float2 fk[8 * 33];
  __shared__ float2 tw[32];
  const int tid = threadIdx.x;
  if (tid < 32) {
    float s, c;
    sincosf(-TWO_PI * (float)tid / 32.0f, &s, &c);
    tw[tid] = make_float2(c, s);
  }
  const int m0 = blockIdx.x * 8;
  const int b = m0 >> 11;
  const int twi = m0 & 2047;
  const int t = twi >> 5;
  const int w0 = twi & 31;
  const int s_ = t >> 5, tm = t & 31;
  {
    const int ci = tid >> 3, wj = tid & 7;
    z2s[wj * 33 + ci] = z2[((long)(b * 32 + ci)) * 2048 + t * 32 + w0 + wj];
  }
  __syncthreads();
  const int m = tid & 7;
  {
    const int cf = tid >> 3;
    float fr = 0, fi = 0;
    int i0 = 0;
#pragma unroll 8
    for (int ci = 0; ci < 32; ++ci) {
      const float2 z = z2s[m * 33 + ci];
      const float2 t0 = tw[i0]; i0 = (i0 + cf) & 31;
      fr = fmaf(z.x, t0.x, fmaf(-z.y, t0.y, fr));
      fi = fmaf(z.x, t0.y, fmaf( z.y, t0.x, fi));
    }
    const float2 k0 = kp[((s_ * 32 + cf) * 32 + tm) * 32 + w0 + m];
    fk[m * 33 + cf] = make_float2(fr * k0.x - fi * k0.y, fr * k0.y + fi * k0.x);
  }
  __syncthreads();
  {
    const int co = tid >> 3;
    float gr = 0, gi = 0;
    int i0 = 0;
#pragma unroll 8
    for (int cf = 0; cf < 32; ++cf) {
      const float2 f = fk[m * 33 + cf];
      const float2 t0 = tw[i0]; i0 = (i0 + co) & 31;
      gr = fmaf(f.x, t0.x, fmaf( f.y, t0.y, gr));
      gi = fmaf(f.y, t0.x, fmaf(-f.x, t0.y, gi));
    }
    const float SC = 1.0f / 8192.0f;
    g[((long)(b * 32 + co)) * 2048 + t * 32 + w0 + m] = make_float2(gr * SC, gi * SC);
  }
}

// kDE2: 512 blocks = (bc, yh); 512 thr. Phase a (R9) -> U[p] regs. Per yq:
// phase b: T -> tst2 (raw f16); phase c: MFMA f16 16x16x32, acc -> ot LDS
// (stride 260: float4-aligned; lg groups 16 banks apart -> free 2-way b32
// write) -> coalesced copy (wave = one 1KB row per float4 round).
// ot overlays gs (dead after phase a). A-frag: row=lane&15,
// k=kk*32+(lane>>4)*8+i; D: col=lane&15, row=(lane>>4)*4+j (m89-verified).
__global__ __launch_bounds__(512) void kDE2(const float2* __restrict__ g,
                                            const _Float16* __restrict__ Bf,
                                            float* __restrict__ out) {
  __shared__ float smem[32 * 260];     // 33.3 KB: gs (16 KB) phase a; ot after
  __shared__ _Float16 tst2[32 * 68];   // 4.25 KB
  float2* gs = (float2*)smem;
  float* ot = smem;
  const int tid = threadIdx.x;
  const int bc = blockIdx.x >> 1, yh = blockIdx.x & 1;
  const int lane = tid & 63, l15 = lane & 15, lg = lane >> 4;
  uint4 bfr[2][2];  // B-frags [nn][kk], constant across yq and bc
#pragma unroll
  for (int nn = 0; nn < 2; ++nn)
#pragma unroll
    for (int kk = 0; kk < 2; ++kk) {
      const int n = 2 * (tid >> 6) + nn;
      bfr[nn][kk] = *(const uint4*)(Bf + (((n * 2 + kk) * 64) + lane) * 8);
    }
  {
    const float4* s4 = (const float4*)(g + (long)bc * 2048);
    float4* d4 = (float4*)gs;
    for (int i = tid; i < 1024; i += 512) d4[i] = s4[i];
  }
  __syncthreads();
  const int w = tid & 31;
  float Ur[2][8], Ui[2][8];
#pragma unroll
  for (int e = 0; e < 2; ++e) {
    const int y1 = (tid + (e << 9)) >> 5;  // 0..31
#pragma unroll
    for (int p = 0; p < 8; ++p) { Ur[e][p] = 0.f; Ui[e][p] = 0.f; }
    float s1, c1;
    sincosf(TWO_PI * (float)y1 / 256.0f, &s1, &c1);
    float pc = 1.f, ps = 0.f;
#pragma unroll
    for (int t = 0; t < 64; ++t) {
      if (t == 32) {
        float s2, c2;
        sincosf(TWO_PI * (float)((224 * y1) & 255) / 256.0f, &s2, &c2);
        pc = c2; ps = s2;
      }
      const float2 v = gs[t * 32 + w];
      const int k = t & 7;
      Ur[e][k] = fmaf(v.x, pc, fmaf(-v.y, ps, Ur[e][k]));
      Ui[e][k] = fmaf(v.x, ps, fmaf( v.y, pc, Ui[e][k]));
      const float tn = fmaf(pc, c1, -ps * s1);
      ps = fmaf(pc, s1, ps * c1);
      pc = tn;
    }
  }
  const long rb0 = (long)bc * 256;
#pragma unroll
  for (int yql = 0; yql < 4; ++yql) {
    const int yq = yh * 4 + yql;
    {  // phase b: T = sum_p U[p] e^{+2pi i p yq/8} -> tst2 (raw f16)
      float sqv, cqv;
      sincosf(TWO_PI * (float)yq / 8.0f, &sqv, &cqv);
#pragma unroll
      for (int e = 0; e < 2; ++e) {
        const int y1 = (tid + (e << 9)) >> 5;
        float tr = 0.f, ti = 0.f, qc = 1.f, qs = 0.f;
#pragma unroll
        for (int p = 0; p < 8; ++p) {
          tr = fmaf(Ur[e][p], qc, fmaf(-Ui[e][p], qs, tr));
          ti = fmaf(Ur[e][p], qs, fmaf( Ui[e][p], qc, ti));
          const float tn = fmaf(qc, cqv, -qs * sqv);
          qs = fmaf(qc, sqv, qs * cqv);
          qc = tn;
        }
        union { unsigned int u; _Float16 h[2]; } hu;
        hu.h[0] = (_Float16)tr;
        hu.h[1] = (_Float16)ti;
        *(unsigned int*)&tst2[y1 * 68 + 2 * w] = hu.u;
      }
    }
    __syncthreads();
    {  // phase c: MFMA -> ot (LDS)
      half8 afr[2][2];  // A-frags [rt][kk]
#pragma unroll
      for (int rt = 0; rt < 2; ++rt)
#pragma unroll
        for (int kk = 0; kk < 2; ++kk) {
          const _Float16* ap = tst2 + (rt * 16 + l15) * 68 + kk * 32 + lg * 8;
          const uint2 lo = *(const uint2*)ap;
          const uint2 hi = *(const uint2*)(ap + 4);
          uint4 u4;
          u4.x = lo.x; u4.y = lo.y; u4.z = hi.x; u4.w = hi.y;
          afr[rt][kk] = __builtin_bit_cast(half8, u4);
        }
#pragma unroll
      for (int rt = 0; rt < 2; ++rt)
#pragma unroll
        for (int nn = 0; nn < 2; ++nn) {
          float4v acc = {0.f, 0.f, 0.f, 0.f};
          acc = __builtin_amdgcn_mfma_f32_16x16x32_f16(
              afr[rt][0], __builtin_bit_cast(half8, bfr[nn][0]), acc, 0, 0, 0);
          acc = __builtin_amdgcn_mfma_f32_16x16x32_f16(
              afr[rt][1], __builtin_bit_cast(half8, bfr[nn][1]), acc, 0, 0, 0);
          const int n = 2 * (tid >> 6) + nn;
          const int col = n * 16 + l15;
          const int r0l = rt * 16 + lg * 4;  // local row
          ot[(r0l + 0) * 260 + col] = acc[0];
          ot[(r0l + 1) * 260 + col] = acc[1];
          ot[(r0l + 2) * 260 + col] = acc[2];
          ot[(r0l + 3) * 260 + col] = acc[3];
        }
    }
    __syncthreads();
    {  // coalesced copy ot -> out rows rbase..rbase+31 (1 KB/wave/round)
      const long rbase = rb0 + yq * 32;
#pragma unroll
      for (int rd = 0; rd < 4; ++rd) {
        const int f = tid + (rd << 9);   // float4 index, 0..2047
        const int row = f >> 6;          // 0..31
        const int c4 = f & 63;           // float4 within row
        const float4 v = *(const float4*)(ot + row * 260 + c4 * 4);
        *(float4*)(out + (rbase + row) * 256 + c4 * 4) = v;
      }
    }
  }
}

extern "C" void kernel_launch(void* const* d_in, const int* in_sizes, int n_in,
                              void* d_out, int out_size, void* d_ws, size_t ws_size,
                              hipStream_t stream) {
  const float* x = (const float*)d_in[0];
  const float* kin = (const float*)d_in[1];
  const float* rp = (const float*)d_in[2];
  float* out = (float*)d_out;
  char* ws = (char*)d_ws;

  float2* z1 = (float2*)(ws);                    // 0..16M (kA w, kB r)
  float2* z2 = (float2*)(ws + (16ull << 20));    // 16..24M (kB w, kC r)
  float2* kp = (float2*)(ws + (24ull << 20));    // 24..24.5M (kPX w, kC r)
  _Float16* Bf = (_Float16*)(ws + (25ull << 20));// 25..25.04M (kPX w, kDE2 r)
  float2* g  = (float2*)(ws);                    // 0..4M (kC w, kDE2 r)

  kPX<<<288, 256, 0, stream>>>(kin, rp, kp, Bf);
  kA<<<2048, 256, 0, stream>>>(x, z1);
  kB<<<512, 256, 0, stream>>>(z1, z2);
  kC<<<2048, 256, 0, stream>>>(z2, kp, g);
  kDE2<<<512, 512, 0, stream>>>(g, Bf, out);
}

// Round 13
// 177.476 us; speedup vs baseline: 1.4750x; 1.0302x over previous
//
#include <hip/hip_runtime.h>
#include <math.h>

// FourierKNOConv2d: x[8,32,256,256] f32, kernel[2,1,32,32,32,2] f32, r scalar.
// out[8,32,256,256] f32.
//   kPX:  (fused) Kp = (kr+i ki)^r [2,32,32,32] c64;  Bf[64x256] f16 (kDE2 B);
//         Ef[256x64] f16 (kA3 B): E1[x][2w+cs] = cs? -sin(2pi wx/256)
//         : cos(2pi wx/256). Both pre-fragmented for mfma 16x16x32.
//   kA3:  Z1ri[8192x64] = X[8192x256] x E1[256x64] via f16 MFMA (M=32/block,
//         N=64, K=256). X->f16 staged fragment-ordered in LDS. Z1ri float
//         layout row*64 + (2w+cs) == float2 z1[row][w].
//   kB:   fused per-bc: z1[bc]->LDS, FFT8 over y2 in LDS, then
//         Z2[bc,t,w] = sum_{y1} S[y1,t&7,w] e^{-2pi i h(t) y1/256}
//   kC:   G = idft32_ch( dft32_ch(z2) * Kp ) / 8192
//   kDE2: per (bc,yh): g[bc]->LDS; phase a: U[p<8] regs; per yq: phase b:
//         T->tst2 (f16); phase c: MFMA -> ot LDS -> coalesced row writes.
// ws map (26.1 MB): z1 @0..16M, z2 @16..24M, kp @24..24.5M, Bf @25..25.04M,
//   Ef @26..26.04M, g @0..4M (over dead z1)

#define TWO_PI 6.28318530717958647692f

typedef _Float16 half8 __attribute__((ext_vector_type(8)));
typedef float float4v __attribute__((ext_vector_type(4)));

// kPX: blocks 0..255 -> kp; 256..287 -> Bf (kDE2, scale folded);
// 288..319 -> Ef (kA3, no scale). Frag layout (validated R10/R11):
// flat = ((ntile*KK + kk)*64 + lane)*8 + i ; k = kk*32 + (lane>>4)*8 + i ;
// col = ntile*16 + (lane&15).
__global__ __launch_bounds__(256) void kPX(const float* __restrict__ kin,
                                           const float* __restrict__ rp,
                                           float2* __restrict__ kp,
                                           _Float16* __restrict__ Bf,
                                           _Float16* __restrict__ Ef) {
  const int tid = threadIdx.x;
  if (blockIdx.x < 256) {
    const int i = blockIdx.x * 256 + tid;  // < 65536
    const float r = rp[0];
    const float kr = kin[2 * i], ki = kin[2 * i + 1];
    const float m2 = fmaf(kr, kr, ki * ki);
    float2 o = make_float2(0.f, 0.f);
    if (m2 > 0.f) {
      const float lm = 0.5f * logf(m2);
      const float ang = atan2f(ki, kr);
      const float mag = expf(r * lm);
      float s, c;
      sincosf(r * ang, &s, &c);
      o = make_float2(mag * c, mag * s);
    }
    kp[i] = o;
  } else if (blockIdx.x < 288) {
    const int f0 = ((blockIdx.x - 256) * 256 + tid) * 2;
#pragma unroll
    for (int u = 0; u < 2; ++u) {
      const int f = f0 + u;
      const int i = f & 7;
      const int lane = (f >> 3) & 63;
      const int kk = (f >> 9) & 1;
      const int n = f >> 10;
      const int k = kk * 32 + ((lane >> 4) << 3) + i;
      const int w = k >> 1, cs = k & 1;
      const int xc = n * 16 + (lane & 15);
      const float sc = (w ? 2.0f : 1.0f) / 256.0f;
      float s, c;
      sincosf(TWO_PI * (float)((w * xc) & 255) / 256.0f, &s, &c);
      Bf[f] = (_Float16)(cs ? (-s * sc) : (c * sc));
    }
  } else {
    // Ef: 32 blocks x 256 thr x 2 = 16384 halves. seg = f>>9 in [0,32):
    // kk = seg&7 (K=256 -> 8 kk), nn = seg>>3 (N=64 -> 4 tiles).
    const int f0 = ((blockIdx.x - 288) * 256 + tid) * 2;
#pragma unroll
    for (int u = 0; u < 2; ++u) {
      const int f = f0 + u;
      const int i = f & 7;
      const int lane = (f >> 3) & 63;
      const int seg = f >> 9;
      const int kk = seg & 7, nn = seg >> 3;
      const int k = kk * 32 + ((lane >> 4) << 3) + i;  // = x
      const int n = nn * 16 + (lane & 15);
      const int w = n >> 1, cs = n & 1;
      float s, c;
      sincosf(TWO_PI * (float)((w * k) & 255) / 256.0f, &s, &c);
      Ef[f] = (_Float16)(cs ? -s : c);
    }
  }
}

// kA3: 2048 blocks x 256 thr (4 waves); block = 32 rows.
// Stage: fr = q*256+tid in [0,1024): rt=fr>>9, kk=(fr>>6)&7, lane=fr&63;
//   read X[row0+rt*16+(fr&15)][kk*32+((fr>>4)&3)*8 ..+8) (2x float4),
//   convert f16, store 16B at As+fr*8 (fragment-ordered -> conflict-free).
// MFMA: wave wv = nn tile; bfr[kk] from Ef (L3-hot); afr via lane-contiguous
//   ds_read_b128; acc over 8 kk; D: col=lane&15, row=(lane>>4)*4+j.
// Z1 write: z1f[row*64 + n] -> 64B contiguous per 16-lane group.
__global__ __launch_bounds__(256) void kA3(const float* __restrict__ x,
                                           const _Float16* __restrict__ Ef,
                                           float* __restrict__ z1f) {
  __shared__ _Float16 As[8192];  // 16 KB, fragment-ordered
  const int tid = threadIdx.x;
  const long row0 = (long)blockIdx.x * 32;
  const int lane = tid & 63, l15 = lane & 15, lg = lane >> 4;
  const int nn = tid >> 6;  // wave = n-tile
  uint4 bfr[8];
#pragma unroll
  for (int kk = 0; kk < 8; ++kk)
    bfr[kk] = *(const uint4*)(Ef + (((nn * 8 + kk) * 64) + lane) * 8);
#pragma unroll
  for (int q = 0; q < 4; ++q) {
    const int fr = q * 256 + tid;
    const int rt = fr >> 9, kk = (fr >> 6) & 7;
    const int lgs = (fr >> 4) & 3, rl = fr & 15;
    const float* xp = x + (row0 + rt * 16 + rl) * 256 + kk * 32 + lgs * 8;
    const float4 v0 = *(const float4*)xp;
    const float4 v1 = *(const float4*)(xp + 4);
    union { uint4 u; _Float16 h[8]; } cv;
    cv.h[0] = (_Float16)v0.x; cv.h[1] = (_Float16)v0.y;
    cv.h[2] = (_Float16)v0.z; cv.h[3] = (_Float16)v0.w;
    cv.h[4] = (_Float16)v1.x; cv.h[5] = (_Float16)v1.y;
    cv.h[6] = (_Float16)v1.z; cv.h[7] = (_Float16)v1.w;
    *(uint4*)(As + fr * 8) = cv.u;
  }
  __syncthreads();
#pragma unroll
  for (int rt = 0; rt < 2; ++rt) {
    float4v acc = {0.f, 0.f, 0.f, 0.f};
#pragma unroll
    for (int kk = 0; kk < 8; ++kk) {
      const half8 afr = *(const half8*)(As + ((rt * 8 + kk) * 64 + lane) * 8);
      acc = __builtin_amdgcn_mfma_f32_16x16x32_f16(
          afr, __builtin_bit_cast(half8, bfr[kk]), acc, 0, 0, 0);
    }
    const int n = nn * 16 + l15;
    float* o = z1f + (row0 + rt * 16 + lg * 4) * 64 + n;
    o[0]       = acc[0];
    o[64]      = acc[1];
    o[2 * 64]  = acc[2];
    o[3 * 64]  = acc[3];
  }
}

// kB: fused kB1+kB2 per bc. 512 blocks = (bc, th); 256 thr; 64 KB LDS.
__global__ __launch_bounds__(256) void kB(const float2* __restrict__ z1,
                                          float2* __restrict__ z2) {
  __shared__ float2 zs[8192];  // 64 KB
  const int tid = threadIdx.x;
  const int bc = blockIdx.x >> 1, th = blockIdx.x & 1;
  {
    const float4* s4 = (const float4*)(z1 + (long)bc * 8192);
    float4* d4 = (float4*)zs;
    for (int i = tid; i < 4096; i += 256) d4[i] = s4[i];
  }
  __syncthreads();
  const float RT = 0.70710678118654752440f;
#pragma unroll
  for (int e = 0; e < 4; ++e) {
    float2* base = zs + tid + (e << 8);  // cell (y1,w), + j*1024 per y2
    float2 a[8];
#pragma unroll
    for (int j = 0; j < 8; ++j) a[j] = base[j * 1024];
    float2 t0 = make_float2(a[0].x + a[4].x, a[0].y + a[4].y);
    float2 t1 = make_float2(a[0].x - a[4].x, a[0].y - a[4].y);
    float2 t2 = make_float2(a[2].x + a[6].x, a[2].y + a[6].y);
    float2 t3 = make_float2(a[2].x - a[6].x, a[2].y - a[6].y);
    const float2 E0 = make_float2(t0.x + t2.x, t0.y + t2.y);
    const float2 E2 = make_float2(t0.x - t2.x, t0.y - t2.y);
    const float2 E1 = make_float2(t1.x + t3.y, t1.y - t3.x);  // t1 - i*t3
    const float2 E3 = make_float2(t1.x - t3.y, t1.y + t3.x);  // t1 + i*t3
    t0 = make_float2(a[1].x + a[5].x, a[1].y + a[5].y);
    t1 = make_float2(a[1].x - a[5].x, a[1].y - a[5].y);
    t2 = make_float2(a[3].x + a[7].x, a[3].y + a[7].y);
    t3 = make_float2(a[3].x - a[7].x, a[3].y - a[7].y);
    const float2 O0 = make_float2(t0.x + t2.x, t0.y + t2.y);
    const float2 O2 = make_float2(t0.x - t2.x, t0.y - t2.y);
    const float2 O1 = make_float2(t1.x + t3.y, t1.y - t3.x);
    const float2 O3 = make_float2(t1.x - t3.y, t1.y + t3.x);
    const float2 B0 = O0;
    const float2 B1 = make_float2(RT * (O1.x + O1.y), RT * (O1.y - O1.x));
    const float2 B2 = make_float2(O2.y, -O2.x);  // -i*O2
    const float2 B3 = make_float2(RT * (O3.y - O3.x), -RT * (O3.x + O3.y));
    base[0]        = make_float2(E0.x + B0.x, E0.y + B0.y);
    base[1 * 1024] = make_float2(E1.x + B1.x, E1.y + B1.y);
    base[2 * 1024] = make_float2(E2.x + B2.x, E2.y + B2.y);
    base[3 * 1024] = make_float2(E3.x + B3.x, E3.y + B3.y);
    base[4 * 1024] = make_float2(E0.x - B0.x, E0.y - B0.y);
    base[5 * 1024] = make_float2(E1.x - B1.x, E1.y - B1.y);
    base[6 * 1024] = make_float2(E2.x - B2.x, E2.y - B2.y);
    base[7 * 1024] = make_float2(E3.x - B3.x, E3.y - B3.y);
  }
  __syncthreads();
  const int w = tid & 31;
  const int lt = tid >> 5;       // 0..7 == p
  const int t0i = th * 32 + lt;  // t = t0i + 8q
  const int hbase = th ? (192 + t0i) : t0i;
  float stc[4], sts[4], pcq[4], psq[4], ar[4], ai[4];
#pragma unroll
  for (int q = 0; q < 4; ++q) {
    sincosf(-TWO_PI * (float)(hbase + 8 * q) / 256.0f, &sts[q], &stc[q]);
    pcq[q] = 1.f; psq[q] = 0.f; ar[q] = 0.f; ai[q] = 0.f;
  }
  const float2* sp = zs + lt * 1024 + w;  // S row y1+32*lt -> + y1*32
  for (int y1 = 0; y1 < 32; ++y1) {
    const float2 v = sp[y1 * 32];
#pragma unroll
    for (int q = 0; q < 4; ++q) {
      ar[q] = fmaf(v.x, pcq[q], fmaf(-v.y, psq[q], ar[q]));
      ai[q] = fmaf(v.x, psq[q], fmaf( v.y, pcq[q], ai[q]));
      const float tn = fmaf(pcq[q], stc[q], -psq[q] * sts[q]);
      psq[q] = fmaf(pcq[q], sts[q], psq[q] * stc[q]);
      pcq[q] = tn;
    }
  }
  float2* dst = z2 + (long)bc * 2048 + t0i * 32 + w;
#pragma unroll
  for (int q = 0; q < 4; ++q) dst[q * 256] = make_float2(ar[q], ai[q]);
}

// kC (R5 proven): 2048 blocks; block = 8 modes (same b,t; 8 w).
__global__ __launch_bounds__(256) void kC(const float2* __restrict__ z2,
                                          const float2* __restrict__ kp,
                                          float2* __restrict__ g) {
  __shared__ float2 z2s[8 * 33];
  __shared__ float2 fk[8 * 33];
  __shared__ float2 tw[32];
  const int tid = threadIdx.x;
  if (tid < 32) {
    float s, c;
    sincosf(-TWO_PI * (float)tid / 32.0f, &s, &c);
    tw[tid] = make_float2(c, s);
  }
  const int m0 = blockIdx.x * 8;
  const int b = m0 >> 11;
  const int twi = m0 & 2047;
  const int t = twi >> 5;
  const int w0 = twi & 31;
  const int s_ = t >> 5, tm = t & 31;
  {
    const int ci = tid >> 3, wj = tid & 7;
    z2s[wj * 33 + ci] = z2[((long)(b * 32 + ci)) * 2048 + t * 32 + w0 + wj];
  }
  __syncthreads();
  const int m = tid & 7;
  {
    const int cf = tid >> 3;
    float fr = 0, fi = 0;
    int i0 = 0;
#pragma unroll 8
    for (int ci = 0; ci < 32; ++ci) {
      const float2 z = z2s[m * 33 + ci];
      const float2 t0 = tw[i0]; i0 = (i0 + cf) & 31;
      fr = fmaf(z.x, t0.x, fmaf(-z.y, t0.y, fr));
      fi = fmaf(z.x, t0.y, fmaf( z.y, t0.x, fi));
    }
    const float2 k0 = kp[((s_ * 32 + cf) * 32 + tm) * 32 + w0 + m];
    fk[m * 33 + cf] = make_float2(fr * k0.x - fi * k0.y, fr * k0.y + fi * k0.x);
  }
  __syncthreads();
  {
    const int co = tid >> 3;
    float gr = 0, gi = 0;
    int i0 = 0;
#pragma unroll 8
    for (int cf = 0; cf < 32; ++cf) {
      const float2 f = fk[m * 33 + cf];
      const float2 t0 = tw[i0]; i0 = (i0 + co) & 31;
      gr = fmaf(f.x, t0.x, fmaf( f.y, t0.y, gr));
      gi = fmaf(f.y, t0.x, fmaf(-f.x, t0.y, gi));
    }
    const float SC = 1.0f / 8192.0f;
    g[((long)(b * 32 + co)) * 2048 + t * 32 + w0 + m] = make_float2(gr * SC, gi * SC);
  }
}

// kDE2 (R11 proven): 512 blocks = (bc, yh); 512 thr. Phase a -> U[p] regs.
// Per yq: phase b: T -> tst2 (f16); phase c: MFMA -> ot LDS -> coalesced copy.
__global__ __launch_bounds__(512) void kDE2(const float2* __restrict__ g,
                                            const _Float16* __restrict__ Bf,
                                            float* __restrict__ out) {
  __shared__ float smem[32 * 260];     // 33.3 KB: gs (16 KB) phase a; ot after
  __shared__ _Float16 tst2[32 * 68];   // 4.25 KB
  float2* gs = (float2*)smem;
  float* ot = smem;
  const int tid = threadIdx.x;
  const int bc = blockIdx.x >> 1, yh = blockIdx.x & 1;
  const int lane = tid & 63, l15 = lane & 15, lg = lane >> 4;
  uint4 bfr[2][2];  // B-frags [nn][kk]
#pragma unroll
  for (int nn = 0; nn < 2; ++nn)
#pragma unroll
    for (int kk = 0; kk < 2; ++kk) {
      const int n = 2 * (tid >> 6) + nn;
      bfr[nn][kk] = *(const uint4*)(Bf + (((n * 2 + kk) * 64) + lane) * 8);
    }
  {
    const float4* s4 = (const float4*)(g + (long)bc * 2048);
    float4* d4 = (float4*)gs;
    for (int i = tid; i < 1024; i += 512) d4[i] = s4[i];
  }
  __syncthreads();
  const int w = tid & 31;
  float Ur[2][8], Ui[2][8];
#pragma unroll
  for (int e = 0; e < 2; ++e) {
    const int y1 = (tid + (e << 9)) >> 5;  // 0..31
#pragma unroll
    for (int p = 0; p < 8; ++p) { Ur[e][p] = 0.f; Ui[e][p] = 0.f; }
    float s1, c1;
    sincosf(TWO_PI * (float)y1 / 256.0f, &s1, &c1);
    float pc = 1.f, ps = 0.f;
#pragma unroll
    for (int t = 0; t < 64; ++t) {
      if (t == 32) {
        float s2, c2;
        sincosf(TWO_PI * (float)((224 * y1) & 255) / 256.0f, &s2, &c2);
        pc = c2; ps = s2;
      }
      const float2 v = gs[t * 32 + w];
      const int k = t & 7;
      Ur[e][k] = fmaf(v.x, pc, fmaf(-v.y, ps, Ur[e][k]));
      Ui[e][k] = fmaf(v.x, ps, fmaf( v.y, pc, Ui[e][k]));
      const float tn = fmaf(pc, c1, -ps * s1);
      ps = fmaf(pc, s1, ps * c1);
      pc = tn;
    }
  }
  const long rb0 = (long)bc * 256;
#pragma unroll
  for (int yql = 0; yql < 4; ++yql) {
    const int yq = yh * 4 + yql;
    {  // phase b: T = sum_p U[p] e^{+2pi i p yq/8} -> tst2 (raw f16)
      float sqv, cqv;
      sincosf(TWO_PI * (float)yq / 8.0f, &sqv, &cqv);
#pragma unroll
      for (int e = 0; e < 2; ++e) {
        const int y1 = (tid + (e << 9)) >> 5;
        float tr = 0.f, ti = 0.f, qc = 1.f, qs = 0.f;
#pragma unroll
        for (int p = 0; p < 8; ++p) {
          tr = fmaf(Ur[e][p], qc, fmaf(-Ui[e][p], qs, tr));
          ti = fmaf(Ur[e][p], qs, fmaf( Ui[e][p], qc, ti));
          const float tn = fmaf(qc, cqv, -qs * sqv);
          qs = fmaf(qc, sqv, qs * cqv);
          qc = tn;
        }
        union { unsigned int u; _Float16 h[2]; } hu;
        hu.h[0] = (_Float16)tr;
        hu.h[1] = (_Float16)ti;
        *(unsigned int*)&tst2[y1 * 68 + 2 * w] = hu.u;
      }
    }
    __syncthreads();
    {  // phase c: MFMA -> ot (LDS)
      half8 afr[2][2];  // A-frags [rt][kk]
#pragma unroll
      for (int rt = 0; rt < 2; ++rt)
#pragma unroll
        for (int kk = 0; kk < 2; ++kk) {
          const _Float16* ap = tst2 + (rt * 16 + l15) * 68 + kk * 32 + lg * 8;
          const uint2 lo = *(const uint2*)ap;
          const uint2 hi = *(const uint2*)(ap + 4);
          uint4 u4;
          u4.x = lo.x; u4.y = lo.y; u4.z = hi.x; u4.w = hi.y;
          afr[rt][kk] = __builtin_bit_cast(half8, u4);
        }
#pragma unroll
      for (int rt = 0; rt < 2; ++rt)
#pragma unroll
        for (int nn = 0; nn < 2; ++nn) {
          float4v acc = {0.f, 0.f, 0.f, 0.f};
          acc = __builtin_amdgcn_mfma_f32_16x16x32_f16(
              afr[rt][0], __builtin_bit_cast(half8, bfr[nn][0]), acc, 0, 0, 0);
          acc = __builtin_amdgcn_mfma_f32_16x16x32_f16(
              afr[rt][1], __builtin_bit_cast(half8, bfr[nn][1]), acc, 0, 0, 0);
          const int n = 2 * (tid >> 6) + nn;
          const int col = n * 16 + l15;
          const int r0l = rt * 16 + lg * 4;  // local row
          ot[(r0l + 0) * 260 + col] = acc[0];
          ot[(r0l + 1) * 260 + col] = acc[1];
          ot[(r0l + 2) * 260 + col] = acc[2];
          ot[(r0l + 3) * 260 + col] = acc[3];
        }
    }
    __syncthreads();
    {  // coalesced copy ot -> out rows rbase..rbase+31
      const long rbase = rb0 + yq * 32;
#pragma unroll
      for (int rd = 0; rd < 4; ++rd) {
        const int f = tid + (rd << 9);   // float4 index, 0..2047
        const int row = f >> 6;          // 0..31
        const int c4 = f & 63;           // float4 within row
        const float4 v = *(const float4*)(ot + row * 260 + c4 * 4);
        *(float4*)(out + (rbase + row) * 256 + c4 * 4) = v;
      }
    }
  }
}

extern "C" void kernel_launch(void* const* d_in, const int* in_sizes, int n_in,
                              void* d_out, int out_size, void* d_ws, size_t ws_size,
                              hipStream_t stream) {
  const float* x = (const float*)d_in[0];
  const float* kin = (const float*)d_in[1];
  const float* rp = (const float*)d_in[2];
  float* out = (float*)d_out;
  char* ws = (char*)d_ws;

  float2* z1 = (float2*)(ws);                    // 0..16M (kA3 w, kB r)
  float2* z2 = (float2*)(ws + (16ull << 20));    // 16..24M (kB w, kC r)
  float2* kp = (float2*)(ws + (24ull << 20));    // 24..24.5M (kPX w, kC r)
  _Float16* Bf = (_Float16*)(ws + (25ull << 20));// 25..25.04M (kPX w, kDE2 r)
  _Float16* Ef = (_Float16*)(ws + (26ull << 20));// 26..26.04M (kPX w, kA3 r)
  float2* g  = (float2*)(ws);                    // 0..4M (kC w, kDE2 r)

  kPX<<<320, 256, 0, stream>>>(kin, rp, kp, Bf, Ef);
  kA3<<<2048, 256, 0, stream>>>(x, Ef, (float*)z1);
  kB<<<512, 256, 0, stream>>>(z1, z2);
  kC<<<2048, 256, 0, stream>>>(z2, kp, g);
  kDE2<<<512, 512, 0, stream>>>(g, Bf, out);
}